// Round 1
// baseline (6886.001 us; speedup 1.0000x reference)
//
#include <hip/hip_runtime.h>

// TransformerXL forward, MI355X. Round 1: all-f32 correctness baseline.
// L=256 qlen, KLEN=512, B=32, E=512, H=8, D=64, FF=2048, NL=4.

// ---------------------------------------------------------------- GEMM (f32)
// C[M,N] = A[M,K] @ B[K,N] (+bias)(+relu). 128x64 tile, BK=16, 256 threads,
// 8x4 acc per thread. Requires M%128==0, N%64==0, K%16==0, lda%4==0.
template<bool BIAS, bool RELU>
__global__ __launch_bounds__(256)
void gemm_f32(const float* __restrict__ A, int lda,
              const float* __restrict__ B, int ldb,
              const float* __restrict__ bias,
              float* __restrict__ C, int ldc,
              int M, int N, int K)
{
    __shared__ __align__(16) float As[16][132];  // transposed A tile [k][m]
    __shared__ __align__(16) float Bs[16][68];
    const int t  = threadIdx.x;
    const int m0 = blockIdx.y * 128;
    const int n0 = blockIdx.x * 64;
    const int ty = t >> 4, tx = t & 15;
    const int ar = t >> 1, acs = (t & 1) << 3;   // A load: row, k-offset
    const int br = t >> 6, bc = t & 63;          // B load
    float acc[8][4];
#pragma unroll
    for (int i = 0; i < 8; ++i)
#pragma unroll
        for (int j = 0; j < 4; ++j) acc[i][j] = 0.f;

    for (int k0 = 0; k0 < K; k0 += 16) {
        const float* Ap = A + (size_t)(m0 + ar) * lda + k0 + acs;
        float4 a0 = *(const float4*)Ap;
        float4 a1 = *(const float4*)(Ap + 4);
        As[acs + 0][ar] = a0.x; As[acs + 1][ar] = a0.y;
        As[acs + 2][ar] = a0.z; As[acs + 3][ar] = a0.w;
        As[acs + 4][ar] = a1.x; As[acs + 5][ar] = a1.y;
        As[acs + 6][ar] = a1.z; As[acs + 7][ar] = a1.w;
#pragma unroll
        for (int u = 0; u < 4; ++u)
            Bs[br + 4 * u][bc] = B[(size_t)(k0 + br + 4 * u) * ldb + n0 + bc];
        __syncthreads();
#pragma unroll
        for (int kk = 0; kk < 16; ++kk) {
            float4 aa0 = *(const float4*)&As[kk][ty * 8];
            float4 aa1 = *(const float4*)&As[kk][ty * 8 + 4];
            float4 bb  = *(const float4*)&Bs[kk][tx * 4];
            float av[8] = {aa0.x, aa0.y, aa0.z, aa0.w, aa1.x, aa1.y, aa1.z, aa1.w};
            float bv[4] = {bb.x, bb.y, bb.z, bb.w};
#pragma unroll
            for (int i = 0; i < 8; ++i)
#pragma unroll
                for (int j = 0; j < 4; ++j)
                    acc[i][j] = fmaf(av[i], bv[j], acc[i][j]);
        }
        __syncthreads();
    }
    float4 b4 = make_float4(0.f, 0.f, 0.f, 0.f);
    if (BIAS) b4 = *(const float4*)&bias[n0 + tx * 4];
#pragma unroll
    for (int i = 0; i < 8; ++i) {
        float4 o;
        o.x = acc[i][0] + b4.x; o.y = acc[i][1] + b4.y;
        o.z = acc[i][2] + b4.z; o.w = acc[i][3] + b4.w;
        if (RELU) {
            o.x = fmaxf(o.x, 0.f); o.y = fmaxf(o.y, 0.f);
            o.z = fmaxf(o.z, 0.f); o.w = fmaxf(o.w, 0.f);
        }
        *(float4*)&C[(size_t)(m0 + ty * 8 + i) * ldc + n0 + tx * 4] = o;
    }
}

// ---------------------------------------------------------------- LayerNorm
// One wave per row of 512. Y = LN(X (+R)) * g + b, optional relu.
__global__ __launch_bounds__(256)
void ln_f32(const float* __restrict__ X, const float* __restrict__ R,
            const float* __restrict__ g, const float* __restrict__ bt,
            float* __restrict__ Y, float eps, int do_relu)
{
    const int row  = blockIdx.x * 4 + (threadIdx.x >> 6);
    const int lane = threadIdx.x & 63;
    const float* xp = X + (size_t)row * 512 + lane * 8;
    float4 x0 = *(const float4*)xp, x1 = *(const float4*)(xp + 4);
    float v[8] = {x0.x, x0.y, x0.z, x0.w, x1.x, x1.y, x1.z, x1.w};
    if (R) {
        const float* rp = R + (size_t)row * 512 + lane * 8;
        float4 r0 = *(const float4*)rp, r1 = *(const float4*)(rp + 4);
        v[0] += r0.x; v[1] += r0.y; v[2] += r0.z; v[3] += r0.w;
        v[4] += r1.x; v[5] += r1.y; v[6] += r1.z; v[7] += r1.w;
    }
    float s = 0.f;
#pragma unroll
    for (int i = 0; i < 8; ++i) s += v[i];
#pragma unroll
    for (int m = 1; m < 64; m <<= 1) s += __shfl_xor(s, m);
    float mean = s * (1.f / 512.f);
    float q = 0.f;
#pragma unroll
    for (int i = 0; i < 8; ++i) { float d = v[i] - mean; q = fmaf(d, d, q); }
#pragma unroll
    for (int m = 1; m < 64; m <<= 1) q += __shfl_xor(q, m);
    float rstd = rsqrtf(q * (1.f / 512.f) + eps);
    float4 g0 = *(const float4*)(g + lane * 8), g1 = *(const float4*)(g + lane * 8 + 4);
    float4 c0 = *(const float4*)(bt + lane * 8), c1 = *(const float4*)(bt + lane * 8 + 4);
    float gv[8] = {g0.x, g0.y, g0.z, g0.w, g1.x, g1.y, g1.z, g1.w};
    float bv[8] = {c0.x, c0.y, c0.z, c0.w, c1.x, c1.y, c1.z, c1.w};
    float o[8];
#pragma unroll
    for (int i = 0; i < 8; ++i) {
        o[i] = (v[i] - mean) * rstd * gv[i] + bv[i];
        if (do_relu) o[i] = fmaxf(o[i], 0.f);
    }
    float* yp = Y + (size_t)row * 512 + lane * 8;
    *(float4*)yp       = make_float4(o[0], o[1], o[2], o[3]);
    *(float4*)(yp + 4) = make_float4(o[4], o[5], o[6], o[7]);
}

// ----------------------------------------------------- stem concat [x | act]
__global__ void build_xcat(const float* __restrict__ x, const int* __restrict__ action,
                           const float* __restrict__ act_emb, float* __restrict__ xcat)
{
    int idx = blockIdx.x * 256 + threadIdx.x;           // 8192*576
    int n = idx / 576, e = idx - n * 576;
    int l = n >> 5, b = n & 31;                         // row = l*32+b
    float v;
    if (e < 512) v = x[((size_t)b * 256 + l) * 512 + e];
    else         v = act_emb[action[b * 32 + (l >> 3)] * 64 + (e - 512)];
    xcat[idx] = v;
}

// ------------------------------------------------- sinusoidal pos embedding
__global__ void build_posemb(float* __restrict__ pe)
{
    int idx = blockIdx.x * 256 + threadIdx.x;           // 512*512
    int j = idx >> 9, c = idx & 511;
    float pf = (float)(511 - j);                        // positions[j] = KLEN-1-j
    int i2 = (c < 256) ? c : c - 256;
    float inv = expf(-(float)i2 * 0.03597789207803197f);  // ln(10000)/256
    float ang = pf * inv;
    pe[idx] = (c < 256) ? sinf(ang) : cosf(ang);
}

// ------------------------------------------------------- fused attention f32
// grid = B*H*(256/BI) blocks, 256 threads. BI=16 query rows, BJ=48 key tile.
// BD via analytic rel-shift: BD[i,j] = (q_i+v_bias) . r[j-i+255] (unmasked).
#define ABI 16
#define ABJ 48
__global__ __launch_bounds__(256)
void attn_f32(const float* __restrict__ q,   // [256*32, 512]  row=i*32+b, col=h*64+d
              const float* __restrict__ kv,  // [512*32, 1024] row=j*32+b, col=h*64+d (k) / 512+h*64+d (v)
              const float* __restrict__ r,   // [512, 512]     row=jr, col=h*64+d
              const float* __restrict__ ub, const float* __restrict__ vb,
              float* __restrict__ ao)        // [256*32, 512]
{
    __shared__ __align__(16) float qu[ABI][68], qv[ABI][68];
    __shared__ __align__(16) float kt[ABJ][68], vt[ABJ][68];
    __shared__ __align__(16) float rt[ABI + ABJ][68];
    __shared__ __align__(16) float sc[ABI][68];
    const int t  = threadIdx.x;
    const int it = blockIdx.x & 15;
    const int bh = blockIdx.x >> 4;
    const int b = bh >> 3, h = bh & 7;
    const int i0 = it << 4;
    for (int e = t; e < ABI * 64; e += 256) {
        int i = e >> 6, d = e & 63;
        float qq = q[((size_t)(i0 + i) * 32 + b) * 512 + h * 64 + d];
        qu[i][d] = qq + ub[h * 64 + d];
        qv[i][d] = qq + vb[h * 64 + d];
    }
    const int i_s = t >> 4, lj = t & 15;
    const int iglob = i0 + i_s;
    float m_run = -3.0e38f, l_run = 0.f;
    float acc0 = 0.f, acc1 = 0.f, acc2 = 0.f, acc3 = 0.f;
    const int njt = (i0 + 271) / ABJ + 1;
    for (int jt = 0; jt < njt; ++jt) {
        const int j0 = jt * ABJ;
        __syncthreads();
        for (int e = t; e < ABJ * 64; e += 256) {
            int jl = e >> 6, d = e & 63;
            int jc = min(j0 + jl, 511);
            size_t rowo = ((size_t)jc * 32 + b) * 1024 + h * 64 + d;
            kt[jl][d] = kv[rowo];
            vt[jl][d] = kv[rowo + 512];
        }
        const int jrb = j0 - i0 + 240;
        for (int e = t; e < (ABI + ABJ) * 64; e += 256) {
            int jl = e >> 6, d = e & 63;
            int jr = jrb + jl; jr = jr < 0 ? 0 : (jr > 511 ? 511 : jr);
            rt[jl][d] = r[(size_t)jr * 512 + h * 64 + d];
        }
        __syncthreads();
        float acj[3] = {0.f, 0.f, 0.f}, bdj[3] = {0.f, 0.f, 0.f};
        const int r0 = lj - i_s + 15;
        for (int d = 0; d < 64; ++d) {
            float uqd = qu[i_s][d], vqd = qv[i_s][d];
#pragma unroll
            for (int jj = 0; jj < 3; ++jj) {
                acj[jj] = fmaf(uqd, kt[lj + 16 * jj][d], acj[jj]);
                bdj[jj] = fmaf(vqd, rt[r0 + 16 * jj][d], bdj[jj]);
            }
        }
        float pj[3]; float rowmax = -3.0e38f;
#pragma unroll
        for (int jj = 0; jj < 3; ++jj) {
            float s = (acj[jj] + bdj[jj]) * 0.125f;
            if (j0 + lj + 16 * jj > iglob + 256) s = -1e30f;
            pj[jj] = s; rowmax = fmaxf(rowmax, s);
        }
#pragma unroll
        for (int mm = 1; mm < 16; mm <<= 1) rowmax = fmaxf(rowmax, __shfl_xor(rowmax, mm));
        float mnew = fmaxf(m_run, rowmax);
        float corr = expf(m_run - mnew);
        float ps = 0.f;
#pragma unroll
        for (int jj = 0; jj < 3; ++jj) {
            float p = expf(pj[jj] - mnew);
            sc[i_s][lj + 16 * jj] = p;
            ps += p;
        }
#pragma unroll
        for (int mm = 1; mm < 16; mm <<= 1) ps += __shfl_xor(ps, mm);
        l_run = l_run * corr + ps;
        m_run = mnew;
        acc0 *= corr; acc1 *= corr; acc2 *= corr; acc3 *= corr;
        __syncthreads();
        for (int jl = 0; jl < ABJ; ++jl) {
            float p = sc[i_s][jl];
            float4 vv = *(const float4*)&vt[jl][lj << 2];
            acc0 = fmaf(p, vv.x, acc0);
            acc1 = fmaf(p, vv.y, acc1);
            acc2 = fmaf(p, vv.z, acc2);
            acc3 = fmaf(p, vv.w, acc3);
        }
    }
    float inv = 1.f / l_run;
    *(float4*)&ao[((size_t)iglob * 32 + b) * 512 + h * 64 + (lj << 2)] =
        make_float4(acc0 * inv, acc1 * inv, acc2 * inv, acc3 * inv);
}

// ------------------------------------------------------------ final transpose
__global__ void final_out(const float* __restrict__ cur, float* __restrict__ out)
{
    int idx = blockIdx.x * 256 + threadIdx.x;   // 8192*512
    int n = idx >> 9, e = idx & 511;
    int l = n >> 5, b = n & 31;
    out[((size_t)b * 256 + l) * 512 + e] = cur[idx];
}

// ---------------------------------------------------------------------------
extern "C" void kernel_launch(void* const* d_in, const int* in_sizes, int n_in,
                              void* d_out, int out_size, void* d_ws, size_t ws_size,
                              hipStream_t stream)
{
    const float* x       = (const float*)d_in[0];
    const int*   action  = (const int*)d_in[1];
    // d_in[2] attn_mask, d_in[3] positions: deterministic, computed in-kernel
    const float* mems    = (const float*)d_in[4];
    const float* act_emb = (const float*)d_in[5];
    const float* stem_w1 = (const float*)d_in[6];
    const float* sln1g   = (const float*)d_in[7];
    const float* sln1b   = (const float*)d_in[8];
    const float* stem_w2 = (const float*)d_in[9];
    const float* sln2g   = (const float*)d_in[10];
    const float* sln2b   = (const float*)d_in[11];
    const float* lnfg    = (const float*)d_in[12];
    const float* lnfb    = (const float*)d_in[13];
    const float* ub      = (const float*)d_in[14];
    const float* vb      = (const float*)d_in[15];
    const float* Wqkv    = (const float*)d_in[16];
    const float* Wr      = (const float*)d_in[17];
    const float* Wo      = (const float*)d_in[18];
    const float* ln1g    = (const float*)d_in[19];
    const float* ln1b    = (const float*)d_in[20];
    const float* W1      = (const float*)d_in[21];
    const float* b1      = (const float*)d_in[22];
    const float* W2      = (const float*)d_in[23];
    const float* b2      = (const float*)d_in[24];
    const float* ln2g    = (const float*)d_in[25];
    const float* ln2b    = (const float*)d_in[26];
    float* out = (float*)d_out;

    // workspace layout (floats). total = 34,078,720 floats = 130 MB
    float* cur = (float*)d_ws;           // 4,194,304  [256*32, 512]
    float* h1  = cur + 4194304;          // 4,194,304
    float* ao  = h1  + 4194304;          // 4,194,304
    float* qb  = ao  + 4194304;          // 4,194,304  q
    float* kv  = qb  + 4194304;          // 16,777,216 [512*32, 1024]
    float* pe  = kv  + 16777216;         // 262,144
    float* rb  = pe  + 262144;           // 262,144
    float* xcat = kv;                    // 8192*576 aliases kv (pre-layer use)
    float* ff1  = kv;                    // 8192*2048 aliases kv (post-attn use)

    dim3 blk(256);
    // ---- stem ----
    build_xcat<<<8192 * 576 / 256, blk, 0, stream>>>(x, action, act_emb, xcat);
    gemm_f32<false, false><<<dim3(8, 64), blk, 0, stream>>>(xcat, 576, stem_w1, 512, nullptr, ao, 512, 8192, 512, 576);
    ln_f32<<<2048, blk, 0, stream>>>(ao, nullptr, sln1g, sln1b, ao, 1e-5f, 1);
    gemm_f32<false, false><<<dim3(8, 64), blk, 0, stream>>>(ao, 512, stem_w2, 512, nullptr, cur, 512, 8192, 512, 512);
    ln_f32<<<2048, blk, 0, stream>>>(cur, nullptr, sln2g, sln2b, cur, 1e-5f, 0);
    ln_f32<<<2048, blk, 0, stream>>>(cur, nullptr, lnfg, lnfb, cur, 1e-6f, 0);
    build_posemb<<<1024, blk, 0, stream>>>(pe);

    for (int l = 0; l < 4; ++l) {
        const float* wqkv = Wqkv + (size_t)l * 512 * 1536;
        // q = cur @ Wqkv[:, :512]
        gemm_f32<false, false><<<dim3(8, 64), blk, 0, stream>>>(cur, 512, wqkv, 1536, nullptr, qb, 512, 8192, 512, 512);
        // kv rows [0,8192) from mems, [8192,16384) from cur; cols 512..1536 of Wqkv
        gemm_f32<false, false><<<dim3(16, 64), blk, 0, stream>>>(mems + (size_t)l * 4194304, 512, wqkv + 512, 1536, nullptr, kv, 1024, 8192, 1024, 512);
        gemm_f32<false, false><<<dim3(16, 64), blk, 0, stream>>>(cur, 512, wqkv + 512, 1536, nullptr, kv + (size_t)8192 * 1024, 1024, 8192, 1024, 512);
        // r = pos_emb @ Wr[l]
        gemm_f32<false, false><<<dim3(8, 4), blk, 0, stream>>>(pe, 512, Wr + (size_t)l * 262144, 512, nullptr, rb, 512, 512, 512, 512);
        attn_f32<<<4096, blk, 0, stream>>>(qb, kv, rb, ub, vb, ao);
        gemm_f32<false, false><<<dim3(8, 64), blk, 0, stream>>>(ao, 512, Wo + (size_t)l * 262144, 512, nullptr, h1, 512, 8192, 512, 512);
        ln_f32<<<2048, blk, 0, stream>>>(h1, cur, ln1g + l * 512, ln1b + l * 512, h1, 1e-5f, 0);
        gemm_f32<true, true><<<dim3(32, 64), blk, 0, stream>>>(h1, 512, W1 + (size_t)l * 1048576, 2048, b1 + l * 2048, ff1, 2048, 8192, 2048, 512);
        gemm_f32<true, false><<<dim3(8, 64), blk, 0, stream>>>(ff1, 2048, W2 + (size_t)l * 1048576, 512, b2 + l * 512, ao, 512, 8192, 512, 2048);
        ln_f32<<<2048, blk, 0, stream>>>(ao, h1, ln2g + l * 512, ln2b + l * 512, cur, 1e-5f, 0);
    }
    final_out<<<16384, blk, 0, stream>>>(cur, out);
}

// Round 2
// 5481.413 us; speedup vs baseline: 1.2562x; 1.2562x over previous
//
#include <hip/hip_runtime.h>

// TransformerXL forward, MI355X. Round 2: bf16 MFMA GEMMs (16x16x32), f32 attn
// with bf16 operands. L=256, KLEN=512, B=32, E=512, H=8, D=64, FF=2048, NL=4.

typedef __attribute__((ext_vector_type(8))) short bf8_t;   // 8 bf16 in 4 VGPRs
typedef __attribute__((ext_vector_type(4))) float f4_t;

__device__ __forceinline__ ushort f2bf(float f) {          // RNE f32->bf16
    uint u = __float_as_uint(f);
    u += 0x7FFFu + ((u >> 16) & 1u);
    return (ushort)(u >> 16);
}
__device__ __forceinline__ float b2f(ushort h) {
    return __uint_as_float(((uint)h) << 16);
}
__device__ __forceinline__ void gload16(const void* g, void* l) {
    __builtin_amdgcn_global_load_lds((const __attribute__((address_space(1))) void*)g,
                                     (__attribute__((address_space(3))) void*)l, 16, 0, 0);
}

// ------------------------------------------------------------ MFMA GEMM bf16
// C[M,N] = A[M,K] @ Bt[N,K]^T (+bias)(+relu). A,Bt bf16 row-major; C f32 or bf16.
// 128x128 tile, BK=32, 256 thr = 4 waves (2x2), each wave 64x64 = 4x4 frags.
// M%128==0, N%128==0, K%32==0, lda/ldb multiples of 8 (16B rows).
template<bool BIAS, bool RELU, bool OUTBF>
__global__ __launch_bounds__(256)
void gemm_bf(const ushort* __restrict__ A, int lda,
             const ushort* __restrict__ Bt, int ldb,
             const float* __restrict__ bias,
             void* __restrict__ Cp, int ldc,
             int M, int N, int K)
{
    __shared__ __align__(16) ushort As[128 * 32];
    __shared__ __align__(16) ushort Bs[128 * 32];
    const int t = threadIdx.x;
    const int w = t >> 6, lane = t & 63;
    const int wr = w >> 1, wc = w & 1;
    const int lr = lane >> 4, lc = lane & 15;
    const int m0 = blockIdx.y * 128, n0 = blockIdx.x * 128;

    const ushort* Ag = A + (size_t)(m0 + w * 32 + (lane >> 2)) * lda + (lane & 3) * 8;
    const ushort* Bg = Bt + (size_t)(n0 + w * 32 + (lane >> 2)) * ldb + (lane & 3) * 8;
    ushort* Asw = As + w * 1024;   // wave-uniform LDS dest (rows w*32..w*32+31)
    ushort* Bsw = Bs + w * 1024;

    f4_t acc[4][4];
#pragma unroll
    for (int i = 0; i < 4; ++i)
#pragma unroll
        for (int j = 0; j < 4; ++j) acc[i][j] = (f4_t){0.f, 0.f, 0.f, 0.f};

    for (int k0 = 0; k0 < K; k0 += 32) {
        gload16(Ag,            Asw);
        gload16(Ag + 16 * lda, Asw + 512);
        gload16(Bg,            Bsw);
        gload16(Bg + 16 * ldb, Bsw + 512);
        Ag += 32; Bg += 32;
        __syncthreads();               // vmcnt(0) drained by compiler before barrier
        bf8_t av[4], bv[4];
#pragma unroll
        for (int i = 0; i < 4; ++i)
            av[i] = *(const bf8_t*)(As + (wr * 64 + i * 16 + lc) * 32 + lr * 8);
#pragma unroll
        for (int j = 0; j < 4; ++j)
            bv[j] = *(const bf8_t*)(Bs + (wc * 64 + j * 16 + lc) * 32 + lr * 8);
#pragma unroll
        for (int i = 0; i < 4; ++i)
#pragma unroll
            for (int j = 0; j < 4; ++j)
                acc[i][j] = __builtin_amdgcn_mfma_f32_16x16x32_bf16(av[i], bv[j], acc[i][j], 0, 0, 0);
        __syncthreads();
    }
    // C/D layout (m89): col = lane&15, row = (lane>>4)*4 + reg
    const int crow = m0 + wr * 64 + lr * 4;
    const int ccol = n0 + wc * 64 + lc;
#pragma unroll
    for (int i = 0; i < 4; ++i) {
#pragma unroll
        for (int j = 0; j < 4; ++j) {
            const int col = ccol + j * 16;
            float bb = 0.f;
            if (BIAS) bb = bias[col];
            f4_t v = acc[i][j];
#pragma unroll
            for (int r = 0; r < 4; ++r) {
                float o = v[r] + bb;
                if (RELU) o = fmaxf(o, 0.f);
                size_t off = (size_t)(crow + i * 16 + r) * ldc + col;
                if (OUTBF) ((ushort*)Cp)[off] = f2bf(o);
                else       ((float*)Cp)[off] = o;
            }
        }
    }
}

// ---------------------------------------------------------------- LayerNorm
// RMODE: 0 = no residual, 1 = f32 residual, 2 = bf16 residual.
template<int RMODE>
__global__ __launch_bounds__(256)
void ln_k(const float* __restrict__ X, const void* __restrict__ Rp,
          const float* __restrict__ g, const float* __restrict__ bt,
          float* __restrict__ Yf, ushort* __restrict__ Yb,
          float eps, int do_relu)
{
    const int row  = blockIdx.x * 4 + (threadIdx.x >> 6);
    const int lane = threadIdx.x & 63;
    const float* xp = X + (size_t)row * 512 + lane * 8;
    float4 x0 = *(const float4*)xp, x1 = *(const float4*)(xp + 4);
    float v[8] = {x0.x, x0.y, x0.z, x0.w, x1.x, x1.y, x1.z, x1.w};
    if (RMODE == 1) {
        const float* rp = (const float*)Rp + (size_t)row * 512 + lane * 8;
        float4 r0 = *(const float4*)rp, r1 = *(const float4*)(rp + 4);
        v[0] += r0.x; v[1] += r0.y; v[2] += r0.z; v[3] += r0.w;
        v[4] += r1.x; v[5] += r1.y; v[6] += r1.z; v[7] += r1.w;
    } else if (RMODE == 2) {
        const ushort* rp = (const ushort*)Rp + (size_t)row * 512 + lane * 8;
        ushort4 r0 = *(const ushort4*)rp, r1 = *(const ushort4*)(rp + 4);
        v[0] += b2f(r0.x); v[1] += b2f(r0.y); v[2] += b2f(r0.z); v[3] += b2f(r0.w);
        v[4] += b2f(r1.x); v[5] += b2f(r1.y); v[6] += b2f(r1.z); v[7] += b2f(r1.w);
    }
    float s = 0.f;
#pragma unroll
    for (int i = 0; i < 8; ++i) s += v[i];
#pragma unroll
    for (int m = 1; m < 64; m <<= 1) s += __shfl_xor(s, m);
    float mean = s * (1.f / 512.f);
    float q = 0.f;
#pragma unroll
    for (int i = 0; i < 8; ++i) { float d = v[i] - mean; q = fmaf(d, d, q); }
#pragma unroll
    for (int m = 1; m < 64; m <<= 1) q += __shfl_xor(q, m);
    float rstd = rsqrtf(q * (1.f / 512.f) + eps);
    float4 g0 = *(const float4*)(g + lane * 8), g1 = *(const float4*)(g + lane * 8 + 4);
    float4 c0 = *(const float4*)(bt + lane * 8), c1 = *(const float4*)(bt + lane * 8 + 4);
    float gv[8] = {g0.x, g0.y, g0.z, g0.w, g1.x, g1.y, g1.z, g1.w};
    float bv[8] = {c0.x, c0.y, c0.z, c0.w, c1.x, c1.y, c1.z, c1.w};
    float o[8];
#pragma unroll
    for (int i = 0; i < 8; ++i) {
        o[i] = (v[i] - mean) * rstd * gv[i] + bv[i];
        if (do_relu) o[i] = fmaxf(o[i], 0.f);
    }
    if (Yf) {
        float* yp = Yf + (size_t)row * 512 + lane * 8;
        *(float4*)yp       = make_float4(o[0], o[1], o[2], o[3]);
        *(float4*)(yp + 4) = make_float4(o[4], o[5], o[6], o[7]);
    }
    if (Yb) {
        ushort* yp = Yb + (size_t)row * 512 + lane * 8;
        ushort4 w0, w1;
        w0.x = f2bf(o[0]); w0.y = f2bf(o[1]); w0.z = f2bf(o[2]); w0.w = f2bf(o[3]);
        w1.x = f2bf(o[4]); w1.y = f2bf(o[5]); w1.z = f2bf(o[6]); w1.w = f2bf(o[7]);
        *(ushort4*)yp       = w0;
        *(ushort4*)(yp + 4) = w1;
    }
}

// ---------------------------------------------- weight transpose+cast f32->bf16
// in [K][N] f32 (batched blockIdx.z) -> out [N][K] bf16
__global__ __launch_bounds__(256)
void wtrans(const float* __restrict__ in, ushort* __restrict__ out, int K, int N)
{
    __shared__ float tl[32][33];
    const size_t bo = (size_t)blockIdx.z * K * N;
    in += bo; out += bo;
    const int k0 = blockIdx.y * 32, n0 = blockIdx.x * 32;
    const int tx = threadIdx.x & 31, ty = threadIdx.x >> 5;
    for (int i = ty; i < 32; i += 8) tl[i][tx] = in[(size_t)(k0 + i) * N + n0 + tx];
    __syncthreads();
    for (int i = ty; i < 32; i += 8) out[(size_t)(n0 + i) * K + k0 + tx] = f2bf(tl[tx][i]);
}

__global__ void convk(const float* __restrict__ in, ushort* __restrict__ out)
{
    int i = (blockIdx.x * 256 + threadIdx.x) * 4;
    float4 v = *(const float4*)(in + i);
    ushort4 o;
    o.x = f2bf(v.x); o.y = f2bf(v.y); o.z = f2bf(v.z); o.w = f2bf(v.w);
    *(ushort4*)(out + i) = o;
}

// ----------------------------------------------------- stem concat [x | act]
__global__ void build_xcat(const float* __restrict__ x, const int* __restrict__ action,
                           const float* __restrict__ act_emb, ushort* __restrict__ xcat)
{
    int idx = blockIdx.x * 256 + threadIdx.x;           // 8192*576
    int n = idx / 576, e = idx - n * 576;
    int l = n >> 5, b = n & 31;                         // row = l*32+b
    float v;
    if (e < 512) v = x[((size_t)b * 256 + l) * 512 + e];
    else         v = act_emb[action[b * 32 + (l >> 3)] * 64 + (e - 512)];
    xcat[idx] = f2bf(v);
}

// ------------------------------------------------- sinusoidal pos embedding
__global__ void build_posemb(ushort* __restrict__ pe)
{
    int idx = blockIdx.x * 256 + threadIdx.x;           // 512*512
    int j = idx >> 9, c = idx & 511;
    float pf = (float)(511 - j);                        // positions[j] = KLEN-1-j
    int i2 = (c < 256) ? c : c - 256;
    float inv = expf(-(float)i2 * 0.03597789207803197f);  // ln(10000)/256
    float ang = pf * inv;
    pe[idx] = f2bf((c < 256) ? sinf(ang) : cosf(ang));
}

// ------------------------------------------------------- fused attention
// bf16 q/kv/r in, bf16 out. BD via analytic rel-shift:
// BD[i,j] = (q_i+v_bias) . r[j-i+255] for the unmasked region.
#define ABI 16
#define ABJ 48
__global__ __launch_bounds__(256)
void attn_bf(const ushort* __restrict__ q,   // [256*32, 512]  row=i*32+b, col=h*64+d
             const ushort* __restrict__ kv,  // [512*32, 1024] row=j*32+b, k/v halves
             const ushort* __restrict__ r,   // [512, 512]
             const float* __restrict__ ub, const float* __restrict__ vb,
             ushort* __restrict__ ao)        // [256*32, 512]
{
    __shared__ __align__(16) float qu[ABI][68], qv[ABI][68];
    __shared__ __align__(16) float kt[ABJ][68], vt[ABJ][68];
    __shared__ __align__(16) float rt[ABI + ABJ][68];
    __shared__ __align__(16) float sc[ABI][68];
    const int t  = threadIdx.x;
    const int it = blockIdx.x & 15;
    const int bh = blockIdx.x >> 4;
    const int b = bh >> 3, h = bh & 7;
    const int i0 = it << 4;
    for (int e = t; e < ABI * 64; e += 256) {
        int i = e >> 6, d = e & 63;
        float qq = b2f(q[((size_t)(i0 + i) * 32 + b) * 512 + h * 64 + d]);
        qu[i][d] = qq + ub[h * 64 + d];
        qv[i][d] = qq + vb[h * 64 + d];
    }
    const int i_s = t >> 4, lj = t & 15;
    const int iglob = i0 + i_s;
    float m_run = -3.0e38f, l_run = 0.f;
    float acc0 = 0.f, acc1 = 0.f, acc2 = 0.f, acc3 = 0.f;
    const int njt = (i0 + 271) / ABJ + 1;
    for (int jt = 0; jt < njt; ++jt) {
        const int j0 = jt * ABJ;
        __syncthreads();
        for (int e = t; e < ABJ * 64; e += 256) {
            int jl = e >> 6, d = e & 63;
            int jc = min(j0 + jl, 511);
            size_t rowo = ((size_t)jc * 32 + b) * 1024 + h * 64 + d;
            kt[jl][d] = b2f(kv[rowo]);
            vt[jl][d] = b2f(kv[rowo + 512]);
        }
        const int jrb = j0 - i0 + 240;
        for (int e = t; e < (ABI + ABJ) * 64; e += 256) {
            int jl = e >> 6, d = e & 63;
            int jr = jrb + jl; jr = jr < 0 ? 0 : (jr > 511 ? 511 : jr);
            rt[jl][d] = b2f(r[(size_t)jr * 512 + h * 64 + d]);
        }
        __syncthreads();
        float acj[3] = {0.f, 0.f, 0.f}, bdj[3] = {0.f, 0.f, 0.f};
        const int r0 = lj - i_s + 15;
        for (int d = 0; d < 64; ++d) {
            float uqd = qu[i_s][d], vqd = qv[i_s][d];
#pragma unroll
            for (int jj = 0; jj < 3; ++jj) {
                acj[jj] = fmaf(uqd, kt[lj + 16 * jj][d], acj[jj]);
                bdj[jj] = fmaf(vqd, rt[r0 + 16 * jj][d], bdj[jj]);
            }
        }
        float pj[3]; float rowmax = -3.0e38f;
#pragma unroll
        for (int jj = 0; jj < 3; ++jj) {
            float s = (acj[jj] + bdj[jj]) * 0.125f;
            if (j0 + lj + 16 * jj > iglob + 256) s = -1e30f;
            pj[jj] = s; rowmax = fmaxf(rowmax, s);
        }
#pragma unroll
        for (int mm = 1; mm < 16; mm <<= 1) rowmax = fmaxf(rowmax, __shfl_xor(rowmax, mm));
        float mnew = fmaxf(m_run, rowmax);
        float corr = expf(m_run - mnew);
        float ps = 0.f;
#pragma unroll
        for (int jj = 0; jj < 3; ++jj) {
            float p = expf(pj[jj] - mnew);
            sc[i_s][lj + 16 * jj] = p;
            ps += p;
        }
#pragma unroll
        for (int mm = 1; mm < 16; mm <<= 1) ps += __shfl_xor(ps, mm);
        l_run = l_run * corr + ps;
        m_run = mnew;
        acc0 *= corr; acc1 *= corr; acc2 *= corr; acc3 *= corr;
        __syncthreads();
        for (int jl = 0; jl < ABJ; ++jl) {
            float p = sc[i_s][jl];
            float4 vv = *(const float4*)&vt[jl][lj << 2];
            acc0 = fmaf(p, vv.x, acc0);
            acc1 = fmaf(p, vv.y, acc1);
            acc2 = fmaf(p, vv.z, acc2);
            acc3 = fmaf(p, vv.w, acc3);
        }
    }
    float inv = 1.f / l_run;
    ushort4 o4;
    o4.x = f2bf(acc0 * inv); o4.y = f2bf(acc1 * inv);
    o4.z = f2bf(acc2 * inv); o4.w = f2bf(acc3 * inv);
    *(ushort4*)&ao[((size_t)iglob * 32 + b) * 512 + h * 64 + (lj << 2)] = o4;
}

// ------------------------------------------------------------ final transpose
__global__ void final_out(const float* __restrict__ cur, float* __restrict__ out)
{
    int idx = blockIdx.x * 256 + threadIdx.x;   // 8192*512
    int n = idx >> 9, e = idx & 511;
    int l = n >> 5, b = n & 31;
    out[((size_t)b * 256 + l) * 512 + e] = cur[idx];
}

// ---------------------------------------------------------------------------
extern "C" void kernel_launch(void* const* d_in, const int* in_sizes, int n_in,
                              void* d_out, int out_size, void* d_ws, size_t ws_size,
                              hipStream_t stream)
{
    const float* x       = (const float*)d_in[0];
    const int*   action  = (const int*)d_in[1];
    const float* mems    = (const float*)d_in[4];
    const float* act_emb = (const float*)d_in[5];
    const float* stem_w1 = (const float*)d_in[6];
    const float* sln1g   = (const float*)d_in[7];
    const float* sln1b   = (const float*)d_in[8];
    const float* stem_w2 = (const float*)d_in[9];
    const float* sln2g   = (const float*)d_in[10];
    const float* sln2b   = (const float*)d_in[11];
    const float* lnfg    = (const float*)d_in[12];
    const float* lnfb    = (const float*)d_in[13];
    const float* ub      = (const float*)d_in[14];
    const float* vb      = (const float*)d_in[15];
    const float* Wqkv    = (const float*)d_in[16];
    const float* Wr      = (const float*)d_in[17];
    const float* Wo      = (const float*)d_in[18];
    const float* ln1g    = (const float*)d_in[19];
    const float* ln1b    = (const float*)d_in[20];
    const float* W1      = (const float*)d_in[21];
    const float* b1      = (const float*)d_in[22];
    const float* W2      = (const float*)d_in[23];
    const float* b2      = (const float*)d_in[24];
    const float* ln2g    = (const float*)d_in[25];
    const float* ln2b    = (const float*)d_in[26];
    float* out = (float*)d_out;

    // ---- workspace layout (bytes), total 121,700,352 ----
    char* W = (char*)d_ws;
    float*  cur32 = (float*) (W + 0);           // 16,777,216  residual (f32)
    float*  g32   = (float*) (W + 16777216);    // 16,777,216  gemm f32 scratch
    ushort* curb  = (ushort*)(W + 33554432);    //  8,388,608  cur bf16
    ushort* h1b   = (ushort*)(W + 41943040);    //  8,388,608  h1 bf16 (= aob alias)
    ushort* qb    = (ushort*)(W + 50331648);    //  8,388,608  q bf16
    ushort* kvb   = (ushort*)(W + 58720256);    // 33,554,432  kv bf16 (ff1b/xcatb/memsb alias)
    ushort* rb    = (ushort*)(W + 92274688);    //    524,288
    ushort* peb   = (ushort*)(W + 92798976);    //    524,288
    ushort* wts   = (ushort*)(W + 93323264);    // 28,377,088  transposed bf16 weights
    ushort* xcatb = kvb;
    ushort* ff1b  = kvb;
    ushort* memsb = kvb + 8388608;              // upper half rows of kv region
    ushort* w1t    = wts;                       // [512][576]
    ushort* w2t    = wts + 294912;              // [512][512]
    ushort* wqkvT  = wts + 557056;              // [4][1536][512]
    ushort* wrT    = wts + 3702784;             // [4][512][512]
    ushort* woT    = wts + 4751360;             // [4][512][512]
    ushort* w1T    = wts + 5799936;             // [4][2048][512]
    ushort* w2T    = wts + 9994240;             // [4][512][2048]

    dim3 blk(256);
    // ---- weight prep (bf16 transpose) ----
    wtrans<<<dim3(16, 18, 1), blk, 0, stream>>>(stem_w1, w1t, 576, 512);
    wtrans<<<dim3(16, 16, 1), blk, 0, stream>>>(stem_w2, w2t, 512, 512);
    wtrans<<<dim3(48, 16, 4), blk, 0, stream>>>(Wqkv, wqkvT, 512, 1536);
    wtrans<<<dim3(16, 16, 4), blk, 0, stream>>>(Wr, wrT, 512, 512);
    wtrans<<<dim3(16, 16, 4), blk, 0, stream>>>(Wo, woT, 512, 512);
    wtrans<<<dim3(64, 16, 4), blk, 0, stream>>>(W1, w1T, 512, 2048);
    wtrans<<<dim3(16, 64, 4), blk, 0, stream>>>(W2, w2T, 2048, 512);
    build_posemb<<<1024, blk, 0, stream>>>(peb);

    // ---- stem ----
    build_xcat<<<18432, blk, 0, stream>>>(x, action, act_emb, xcatb);
    gemm_bf<false, false, false><<<dim3(4, 64), blk, 0, stream>>>(xcatb, 576, w1t, 576, nullptr, g32, 512, 8192, 512, 576);
    ln_k<0><<<2048, blk, 0, stream>>>(g32, nullptr, sln1g, sln1b, nullptr, curb, 1e-5f, 1);
    gemm_bf<false, false, false><<<dim3(4, 64), blk, 0, stream>>>(curb, 512, w2t, 512, nullptr, g32, 512, 8192, 512, 512);
    ln_k<0><<<2048, blk, 0, stream>>>(g32, nullptr, sln2g, sln2b, cur32, nullptr, 1e-5f, 0);
    ln_k<0><<<2048, blk, 0, stream>>>(cur32, nullptr, lnfg, lnfb, cur32, curb, 1e-6f, 0);

    for (int l = 0; l < 4; ++l) {
        const ushort* wqkvT_l = wqkvT + (size_t)l * 786432;
        // mems[l] -> bf16 (upper kv region; dead before kv rows 8192+ written)
        convk<<<4096, blk, 0, stream>>>(mems + (size_t)l * 4194304, memsb);
        gemm_bf<false, false, true><<<dim3(4, 64), blk, 0, stream>>>(curb, 512, wqkvT_l, 512, nullptr, qb, 512, 8192, 512, 512);
        gemm_bf<false, false, true><<<dim3(8, 64), blk, 0, stream>>>(memsb, 512, wqkvT_l + 262144, 512, nullptr, kvb, 1024, 8192, 1024, 512);
        gemm_bf<false, false, true><<<dim3(8, 64), blk, 0, stream>>>(curb, 512, wqkvT_l + 262144, 512, nullptr, kvb + (size_t)8192 * 1024, 1024, 8192, 1024, 512);
        gemm_bf<false, false, true><<<dim3(4, 4), blk, 0, stream>>>(peb, 512, wrT + (size_t)l * 262144, 512, nullptr, rb, 512, 512, 512, 512);
        attn_bf<<<4096, blk, 0, stream>>>(qb, kvb, rb, ub, vb, h1b /*aob*/);
        gemm_bf<false, false, false><<<dim3(4, 64), blk, 0, stream>>>(h1b, 512, woT + (size_t)l * 262144, 512, nullptr, g32, 512, 8192, 512, 512);
        ln_k<1><<<2048, blk, 0, stream>>>(g32, cur32, ln1g + l * 512, ln1b + l * 512, nullptr, h1b, 1e-5f, 0);
        gemm_bf<true, true, true><<<dim3(16, 64), blk, 0, stream>>>(h1b, 512, w1T + (size_t)l * 1048576, 512, b1 + l * 2048, ff1b, 2048, 8192, 2048, 512);
        gemm_bf<true, false, false><<<dim3(4, 64), blk, 0, stream>>>(ff1b, 2048, w2T + (size_t)l * 1048576, 2048, b2 + l * 512, g32, 512, 8192, 512, 2048);
        ln_k<2><<<2048, blk, 0, stream>>>(g32, h1b, ln2g + l * 512, ln2b + l * 512, cur32, curb, 1e-5f, 0);
    }
    final_out<<<16384, blk, 0, stream>>>(cur32, out);
}

// Round 3
// 1054.102 us; speedup vs baseline: 6.5326x; 5.2001x over previous
//
#include <hip/hip_runtime.h>

// TransformerXL forward, MI355X. Round 3: MFMA flash attention + bf16 MFMA GEMMs.
// L=256, KLEN=512, B=32, E=512, H=8, D=64, FF=2048, NL=4.

typedef __attribute__((ext_vector_type(8))) short bf8_t;   // 8 bf16 in 4 VGPRs
typedef __attribute__((ext_vector_type(4))) float f4_t;

__device__ __forceinline__ ushort f2bf(float f) {          // RNE f32->bf16
    uint u = __float_as_uint(f);
    u += 0x7FFFu + ((u >> 16) & 1u);
    return (ushort)(u >> 16);
}
__device__ __forceinline__ float b2f(ushort h) {
    return __uint_as_float(((uint)h) << 16);
}
__device__ __forceinline__ void gload16(const void* g, void* l) {
    __builtin_amdgcn_global_load_lds((const __attribute__((address_space(1))) void*)g,
                                     (__attribute__((address_space(3))) void*)l, 16, 0, 0);
}

// ------------------------------------------------------------ MFMA GEMM bf16
template<bool BIAS, bool RELU, bool OUTBF>
__global__ __launch_bounds__(256)
void gemm_bf(const ushort* __restrict__ A, int lda,
             const ushort* __restrict__ Bt, int ldb,
             const float* __restrict__ bias,
             void* __restrict__ Cp, int ldc,
             int M, int N, int K)
{
    __shared__ __align__(16) ushort As[128 * 32];
    __shared__ __align__(16) ushort Bs[128 * 32];
    const int t = threadIdx.x;
    const int w = t >> 6, lane = t & 63;
    const int wr = w >> 1, wc = w & 1;
    const int lr = lane >> 4, lc = lane & 15;
    const int m0 = blockIdx.y * 128, n0 = blockIdx.x * 128;

    const ushort* Ag = A + (size_t)(m0 + w * 32 + (lane >> 2)) * lda + (lane & 3) * 8;
    const ushort* Bg = Bt + (size_t)(n0 + w * 32 + (lane >> 2)) * ldb + (lane & 3) * 8;
    ushort* Asw = As + w * 1024;
    ushort* Bsw = Bs + w * 1024;

    f4_t acc[4][4];
#pragma unroll
    for (int i = 0; i < 4; ++i)
#pragma unroll
        for (int j = 0; j < 4; ++j) acc[i][j] = (f4_t){0.f, 0.f, 0.f, 0.f};

    for (int k0 = 0; k0 < K; k0 += 32) {
        gload16(Ag,            Asw);
        gload16(Ag + 16 * lda, Asw + 512);
        gload16(Bg,            Bsw);
        gload16(Bg + 16 * ldb, Bsw + 512);
        Ag += 32; Bg += 32;
        __syncthreads();
        bf8_t av[4], bv[4];
#pragma unroll
        for (int i = 0; i < 4; ++i)
            av[i] = *(const bf8_t*)(As + (wr * 64 + i * 16 + lc) * 32 + lr * 8);
#pragma unroll
        for (int j = 0; j < 4; ++j)
            bv[j] = *(const bf8_t*)(Bs + (wc * 64 + j * 16 + lc) * 32 + lr * 8);
#pragma unroll
        for (int i = 0; i < 4; ++i)
#pragma unroll
            for (int j = 0; j < 4; ++j)
                acc[i][j] = __builtin_amdgcn_mfma_f32_16x16x32_bf16(av[i], bv[j], acc[i][j], 0, 0, 0);
        __syncthreads();
    }
    const int crow = m0 + wr * 64 + lr * 4;
    const int ccol = n0 + wc * 64 + lc;
#pragma unroll
    for (int i = 0; i < 4; ++i) {
#pragma unroll
        for (int j = 0; j < 4; ++j) {
            const int col = ccol + j * 16;
            float bb = 0.f;
            if (BIAS) bb = bias[col];
            f4_t v = acc[i][j];
#pragma unroll
            for (int r = 0; r < 4; ++r) {
                float o = v[r] + bb;
                if (RELU) o = fmaxf(o, 0.f);
                size_t off = (size_t)(crow + i * 16 + r) * ldc + col;
                if (OUTBF) ((ushort*)Cp)[off] = f2bf(o);
                else       ((float*)Cp)[off] = o;
            }
        }
    }
}

// ---------------------------------------------------------------- LayerNorm
template<int RMODE>
__global__ __launch_bounds__(256)
void ln_k(const float* __restrict__ X, const void* __restrict__ Rp,
          const float* __restrict__ g, const float* __restrict__ bt,
          float* __restrict__ Yf, ushort* __restrict__ Yb,
          float eps, int do_relu)
{
    const int row  = blockIdx.x * 4 + (threadIdx.x >> 6);
    const int lane = threadIdx.x & 63;
    const float* xp = X + (size_t)row * 512 + lane * 8;
    float4 x0 = *(const float4*)xp, x1 = *(const float4*)(xp + 4);
    float v[8] = {x0.x, x0.y, x0.z, x0.w, x1.x, x1.y, x1.z, x1.w};
    if (RMODE == 1) {
        const float* rp = (const float*)Rp + (size_t)row * 512 + lane * 8;
        float4 r0 = *(const float4*)rp, r1 = *(const float4*)(rp + 4);
        v[0] += r0.x; v[1] += r0.y; v[2] += r0.z; v[3] += r0.w;
        v[4] += r1.x; v[5] += r1.y; v[6] += r1.z; v[7] += r1.w;
    } else if (RMODE == 2) {
        const ushort* rp = (const ushort*)Rp + (size_t)row * 512 + lane * 8;
        ushort4 r0 = *(const ushort4*)rp, r1 = *(const ushort4*)(rp + 4);
        v[0] += b2f(r0.x); v[1] += b2f(r0.y); v[2] += b2f(r0.z); v[3] += b2f(r0.w);
        v[4] += b2f(r1.x); v[5] += b2f(r1.y); v[6] += b2f(r1.z); v[7] += b2f(r1.w);
    }
    float s = 0.f;
#pragma unroll
    for (int i = 0; i < 8; ++i) s += v[i];
#pragma unroll
    for (int m = 1; m < 64; m <<= 1) s += __shfl_xor(s, m);
    float mean = s * (1.f / 512.f);
    float q = 0.f;
#pragma unroll
    for (int i = 0; i < 8; ++i) { float d = v[i] - mean; q = fmaf(d, d, q); }
#pragma unroll
    for (int m = 1; m < 64; m <<= 1) q += __shfl_xor(q, m);
    float rstd = rsqrtf(q * (1.f / 512.f) + eps);
    float4 g0 = *(const float4*)(g + lane * 8), g1 = *(const float4*)(g + lane * 8 + 4);
    float4 c0 = *(const float4*)(bt + lane * 8), c1 = *(const float4*)(bt + lane * 8 + 4);
    float gv[8] = {g0.x, g0.y, g0.z, g0.w, g1.x, g1.y, g1.z, g1.w};
    float bv[8] = {c0.x, c0.y, c0.z, c0.w, c1.x, c1.y, c1.z, c1.w};
    float o[8];
#pragma unroll
    for (int i = 0; i < 8; ++i) {
        o[i] = (v[i] - mean) * rstd * gv[i] + bv[i];
        if (do_relu) o[i] = fmaxf(o[i], 0.f);
    }
    if (Yf) {
        float* yp = Yf + (size_t)row * 512 + lane * 8;
        *(float4*)yp       = make_float4(o[0], o[1], o[2], o[3]);
        *(float4*)(yp + 4) = make_float4(o[4], o[5], o[6], o[7]);
    }
    if (Yb) {
        ushort* yp = Yb + (size_t)row * 512 + lane * 8;
        ushort4 w0, w1;
        w0.x = f2bf(o[0]); w0.y = f2bf(o[1]); w0.z = f2bf(o[2]); w0.w = f2bf(o[3]);
        w1.x = f2bf(o[4]); w1.y = f2bf(o[5]); w1.z = f2bf(o[6]); w1.w = f2bf(o[7]);
        *(ushort4*)yp       = w0;
        *(ushort4*)(yp + 4) = w1;
    }
}

// ---------------------------------------------- weight transpose+cast f32->bf16
__global__ __launch_bounds__(256)
void wtrans(const float* __restrict__ in, ushort* __restrict__ out, int K, int N)
{
    __shared__ float tl[32][33];
    const size_t bo = (size_t)blockIdx.z * K * N;
    in += bo; out += bo;
    const int k0 = blockIdx.y * 32, n0 = blockIdx.x * 32;
    const int tx = threadIdx.x & 31, ty = threadIdx.x >> 5;
    for (int i = ty; i < 32; i += 8) tl[i][tx] = in[(size_t)(k0 + i) * N + n0 + tx];
    __syncthreads();
    for (int i = ty; i < 32; i += 8) out[(size_t)(n0 + i) * K + k0 + tx] = f2bf(tl[tx][i]);
}

__global__ void convk(const float* __restrict__ in, ushort* __restrict__ out)
{
    int i = (blockIdx.x * 256 + threadIdx.x) * 4;
    float4 v = *(const float4*)(in + i);
    ushort4 o;
    o.x = f2bf(v.x); o.y = f2bf(v.y); o.z = f2bf(v.z); o.w = f2bf(v.w);
    *(ushort4*)(out + i) = o;
}

// ----------------------------------------------------- stem concat [x | act]
__global__ void build_xcat(const float* __restrict__ x, const int* __restrict__ action,
                           const float* __restrict__ act_emb, ushort* __restrict__ xcat)
{
    int idx = blockIdx.x * 256 + threadIdx.x;           // 8192*576
    int n = idx / 576, e = idx - n * 576;
    int l = n >> 5, b = n & 31;
    float v;
    if (e < 512) v = x[((size_t)b * 256 + l) * 512 + e];
    else         v = act_emb[action[b * 32 + (l >> 3)] * 64 + (e - 512)];
    xcat[idx] = f2bf(v);
}

// ------------------------------------------------- sinusoidal pos embedding
__global__ void build_posemb(ushort* __restrict__ pe)
{
    int idx = blockIdx.x * 256 + threadIdx.x;           // 512*512
    int j = idx >> 9, c = idx & 511;
    float pf = (float)(511 - j);
    int i2 = (c < 256) ? c : c - 256;
    float inv = expf(-(float)i2 * 0.03597789207803197f);
    float ang = pf * inv;
    pe[idx] = f2bf((c < 256) ? sinf(ang) : cosf(ang));
}

// --------------------------------------------------- MFMA flash attention
// block = (b*8+h)*2 + ihalf; 512 thr = 8 waves, wave w owns q-rows iw..iw+15.
// AC[i,j] = (q_i+u).k_j ; BD[i,j] = (q_i+v).r[j-i+255] (analytic rel-shift),
// computed as banded BDfull mfma + in-wave lane-rotation shuffle.
__global__ __launch_bounds__(512)
void attn_mfma(const ushort* __restrict__ qb,   // [256*32][512], col h*64+d
               const ushort* __restrict__ kvb,  // [512*32][1024], k | v halves
               const ushort* __restrict__ rb,   // [512][512]
               const float* __restrict__ ub, const float* __restrict__ vb,
               ushort* __restrict__ ao)         // [256*32][512]
{
    __shared__ __align__(16) ushort Ks[64][72];     // K tile  [j][d]
    __shared__ __align__(16) ushort Vs[64][72];     // V^T tile [d][j]
    __shared__ __align__(16) ushort Rs[192][72];    // r band  [band row][d]
    __shared__ __align__(16) ushort Ps[8][16][72];  // per-wave P / O bounce
    const int t = threadIdx.x;
    const int wv = t >> 6, lane = t & 63;
    const int lc = lane & 15, lr = lane >> 4;
    const int bh = (int)blockIdx.x >> 1, ihalf = blockIdx.x & 1;
    const int b = bh >> 3, h = bh & 7;
    const int i0 = ihalf << 7;
    const int iw = i0 + wv * 16;

    // q A-fragments (lane: row=lc, k-slice lr*8), with u/v bias folded
    bf8_t au[2], aw[2];
#pragma unroll
    for (int kk = 0; kk < 2; ++kk) {
        const ushort* qp = qb + ((size_t)(iw + lc) * 32 + b) * 512 + h * 64 + kk * 32 + lr * 8;
        bf8_t q8 = *(const bf8_t*)qp;
        const float* up = ub + h * 64 + kk * 32 + lr * 8;
        const float* vp = vb + h * 64 + kk * 32 + lr * 8;
#pragma unroll
        for (int e = 0; e < 8; ++e) {
            float qf = b2f((ushort)q8[e]);
            au[kk][e] = (short)f2bf(qf + up[e]);
            aw[kk][e] = (short)f2bf(qf + vp[e]);
        }
    }

    f4_t o[4];
#pragma unroll
    for (int d = 0; d < 4; ++d) o[d] = (f4_t){0.f, 0.f, 0.f, 0.f};
    float mrun[4] = {-3.0e38f, -3.0e38f, -3.0e38f, -3.0e38f};
    float lrun[4] = {0.f, 0.f, 0.f, 0.f};

    const int njt = ihalf ? 8 : 6;
    for (int jt = 0; jt < njt; ++jt) {
        const int j0 = jt << 6;
        __syncthreads();
        {   // ---- cooperative staging ----
            const int jl = t >> 3, d0 = (t & 7) * 8;
            *(bf8_t*)&Ks[jl][d0] =
                *(const bf8_t*)(kvb + ((size_t)(j0 + jl) * 32 + b) * 1024 + h * 64 + d0);
            // V transposed: row mapping g*8+wv keeps scalar writes spread over banks
            const int vrow = ((t >> 3) & 7) * 8 + wv;
            bf8_t vv = *(const bf8_t*)(kvb + ((size_t)(j0 + vrow) * 32 + b) * 1024 + 512 + h * 64 + d0);
#pragma unroll
            for (int e = 0; e < 8; ++e) Vs[d0 + e][vrow] = (ushort)vv[e];
            const int rbase0 = j0 - i0 + 128;
#pragma unroll
            for (int p = 0; p < 3; ++p) {
                const int rr = p * 64 + jl;
                const int jr = min(rbase0 + rr, 511);
                *(bf8_t*)&Rs[rr][d0] = *(const bf8_t*)(rb + (size_t)jr * 512 + h * 64 + d0);
            }
        }
        __syncthreads();
        if (j0 <= iw + 271) {            // wave-uniform skip of fully-masked tiles
            f4_t acf[4], bdf[5];
#pragma unroll
            for (int jj = 0; jj < 4; ++jj) acf[jj] = (f4_t){0.f, 0.f, 0.f, 0.f};
#pragma unroll
            for (int fj = 0; fj < 5; ++fj) bdf[fj] = (f4_t){0.f, 0.f, 0.f, 0.f};
#pragma unroll
            for (int jj = 0; jj < 4; ++jj)
#pragma unroll
                for (int kk = 0; kk < 2; ++kk) {
                    bf8_t kf = *(const bf8_t*)&Ks[jj * 16 + lc][kk * 32 + lr * 8];
                    acf[jj] = __builtin_amdgcn_mfma_f32_16x16x32_bf16(au[kk], kf, acf[jj], 0, 0, 0);
                }
            const int rboff = 112 - wv * 16;
#pragma unroll
            for (int fj = 0; fj < 5; ++fj)
#pragma unroll
                for (int kk = 0; kk < 2; ++kk) {
                    bf8_t rf = *(const bf8_t*)&Rs[rboff + fj * 16 + lc][kk * 32 + lr * 8];
                    bdf[fj] = __builtin_amdgcn_mfma_f32_16x16x32_bf16(aw[kk], rf, bdf[fj], 0, 0, 0);
                }
            // ---- scores: rel-shift shuffle + mask + online softmax ----
            float pm[4][4];
            float mt[4] = {-3.0e38f, -3.0e38f, -3.0e38f, -3.0e38f};
            const int jbase = j0 + lc - iw - 256;   // masked iff jbase + jj*16 > il
#pragma unroll
            for (int jj = 0; jj < 4; ++jj)
#pragma unroll
                for (int rg = 0; rg < 4; ++rg) {
                    const int il = lr * 4 + rg;
                    const int srcl = (lane & 48) | ((lc + 15 - il) & 15);
                    float lo = __shfl(bdf[jj][rg], srcl, 64);
                    float hi = __shfl(bdf[jj + 1][rg], srcl, 64);
                    float bd = (lc > il) ? hi : lo;
                    float s = (acf[jj][rg] + bd) * 0.125f;
                    if (jbase + jj * 16 > il) s = -1e30f;
                    pm[jj][rg] = s;
                    mt[rg] = fmaxf(mt[rg], s);
                }
            float corr[4];
#pragma unroll
            for (int rg = 0; rg < 4; ++rg) {
#pragma unroll
                for (int mm = 1; mm < 16; mm <<= 1)
                    mt[rg] = fmaxf(mt[rg], __shfl_xor(mt[rg], mm, 64));
                float mnew = fmaxf(mrun[rg], mt[rg]);
                corr[rg] = __expf(mrun[rg] - mnew);
                mrun[rg] = mnew;
            }
            float ps4[4] = {0.f, 0.f, 0.f, 0.f};
#pragma unroll
            for (int jj = 0; jj < 4; ++jj)
#pragma unroll
                for (int rg = 0; rg < 4; ++rg) {
                    float p = __expf(pm[jj][rg] - mrun[rg]);
                    ps4[rg] += p;
                    Ps[wv][lr * 4 + rg][jj * 16 + lc] = f2bf(p);
                }
#pragma unroll
            for (int rg = 0; rg < 4; ++rg) {
#pragma unroll
                for (int mm = 1; mm < 16; mm <<= 1)
                    ps4[rg] += __shfl_xor(ps4[rg], mm, 64);
                lrun[rg] = lrun[rg] * corr[rg] + ps4[rg];
            }
            // rescale O^T (col i = lc) by corr of row lc
            float c0 = __shfl(corr[0], (lc >> 2) << 4, 64);
            float c1 = __shfl(corr[1], (lc >> 2) << 4, 64);
            float c2 = __shfl(corr[2], (lc >> 2) << 4, 64);
            float c3 = __shfl(corr[3], (lc >> 2) << 4, 64);
            float myc = (lc & 2) ? ((lc & 1) ? c3 : c2) : ((lc & 1) ? c1 : c0);
#pragma unroll
            for (int db = 0; db < 4; ++db)
#pragma unroll
                for (int rg = 0; rg < 4; ++rg) o[db][rg] *= myc;
            // PV: O^T += V^T(A) . P(B)
#pragma unroll
            for (int kb = 0; kb < 2; ++kb) {
                bf8_t pf = *(const bf8_t*)&Ps[wv][lc][kb * 32 + lr * 8];
#pragma unroll
                for (int db = 0; db < 4; ++db) {
                    bf8_t vf = *(const bf8_t*)&Vs[db * 16 + lc][kb * 32 + lr * 8];
                    o[db] = __builtin_amdgcn_mfma_f32_16x16x32_bf16(vf, pf, o[db], 0, 0, 0);
                }
            }
        }
    }
    // ---- epilogue: scale by 1/l, bounce O^T -> row-major via Ps, store ----
    float i4[4];
#pragma unroll
    for (int rg = 0; rg < 4; ++rg) i4[rg] = 1.f / lrun[rg];
    float s0 = __shfl(i4[0], (lc >> 2) << 4, 64);
    float s1 = __shfl(i4[1], (lc >> 2) << 4, 64);
    float s2 = __shfl(i4[2], (lc >> 2) << 4, 64);
    float s3 = __shfl(i4[3], (lc >> 2) << 4, 64);
    float myi = (lc & 2) ? ((lc & 1) ? s3 : s2) : ((lc & 1) ? s1 : s0);
#pragma unroll
    for (int db = 0; db < 4; ++db)
#pragma unroll
        for (int rg = 0; rg < 4; ++rg)
            Ps[wv][lc][db * 16 + lr * 4 + rg] = f2bf(o[db][rg] * myi);
    const int il2 = lane >> 2, dsg = (lane & 3) << 4;
    bf8_t e0 = *(const bf8_t*)&Ps[wv][il2][dsg];
    bf8_t e1 = *(const bf8_t*)&Ps[wv][il2][dsg + 8];
    ushort* dst = ao + ((size_t)(iw + il2) * 32 + b) * 512 + h * 64 + dsg;
    *(bf8_t*)dst = e0;
    *(bf8_t*)(dst + 8) = e1;
}

// ------------------------------------------------------------ final transpose
__global__ void final_out(const float* __restrict__ cur, float* __restrict__ out)
{
    int idx = blockIdx.x * 256 + threadIdx.x;   // 8192*512
    int n = idx >> 9, e = idx & 511;
    int l = n >> 5, b = n & 31;
    out[((size_t)b * 256 + l) * 512 + e] = cur[idx];
}

// ---------------------------------------------------------------------------
extern "C" void kernel_launch(void* const* d_in, const int* in_sizes, int n_in,
                              void* d_out, int out_size, void* d_ws, size_t ws_size,
                              hipStream_t stream)
{
    const float* x       = (const float*)d_in[0];
    const int*   action  = (const int*)d_in[1];
    const float* mems    = (const float*)d_in[4];
    const float* act_emb = (const float*)d_in[5];
    const float* stem_w1 = (const float*)d_in[6];
    const float* sln1g   = (const float*)d_in[7];
    const float* sln1b   = (const float*)d_in[8];
    const float* stem_w2 = (const float*)d_in[9];
    const float* sln2g   = (const float*)d_in[10];
    const float* sln2b   = (const float*)d_in[11];
    const float* lnfg    = (const float*)d_in[12];
    const float* lnfb    = (const float*)d_in[13];
    const float* ub      = (const float*)d_in[14];
    const float* vb      = (const float*)d_in[15];
    const float* Wqkv    = (const float*)d_in[16];
    const float* Wr      = (const float*)d_in[17];
    const float* Wo      = (const float*)d_in[18];
    const float* ln1g    = (const float*)d_in[19];
    const float* ln1b    = (const float*)d_in[20];
    const float* W1      = (const float*)d_in[21];
    const float* b1      = (const float*)d_in[22];
    const float* W2      = (const float*)d_in[23];
    const float* b2      = (const float*)d_in[24];
    const float* ln2g    = (const float*)d_in[25];
    const float* ln2b    = (const float*)d_in[26];
    float* out = (float*)d_out;

    // ---- workspace layout (bytes), total 121,700,352 ----
    char* W = (char*)d_ws;
    float*  cur32 = (float*) (W + 0);           // 16 MB residual f32
    float*  g32   = (float*) (W + 16777216);    // 16 MB gemm f32 scratch
    ushort* curb  = (ushort*)(W + 33554432);    //  8 MB cur bf16
    ushort* h1b   = (ushort*)(W + 41943040);    //  8 MB h1/ao bf16
    ushort* qb    = (ushort*)(W + 50331648);    //  8 MB q bf16
    ushort* kvb   = (ushort*)(W + 58720256);    // 32 MB kv bf16 (ff1b/xcatb/memsb alias)
    ushort* rb    = (ushort*)(W + 92274688);    // 512 KB
    ushort* peb   = (ushort*)(W + 92798976);    // 512 KB
    ushort* wts   = (ushort*)(W + 93323264);    // 27 MB transposed bf16 weights
    ushort* xcatb = kvb;
    ushort* ff1b  = kvb;
    ushort* memsb = kvb + 8388608;
    ushort* w1t    = wts;                       // [512][576]
    ushort* w2t    = wts + 294912;              // [512][512]
    ushort* wqkvT  = wts + 557056;              // [4][1536][512]
    ushort* wrT    = wts + 3702784;             // [4][512][512]
    ushort* woT    = wts + 4751360;             // [4][512][512]
    ushort* w1T    = wts + 5799936;             // [4][2048][512]
    ushort* w2T    = wts + 9994240;             // [4][512][2048]

    dim3 blk(256);
    wtrans<<<dim3(16, 18, 1), blk, 0, stream>>>(stem_w1, w1t, 576, 512);
    wtrans<<<dim3(16, 16, 1), blk, 0, stream>>>(stem_w2, w2t, 512, 512);
    wtrans<<<dim3(48, 16, 4), blk, 0, stream>>>(Wqkv, wqkvT, 512, 1536);
    wtrans<<<dim3(16, 16, 4), blk, 0, stream>>>(Wr, wrT, 512, 512);
    wtrans<<<dim3(16, 16, 4), blk, 0, stream>>>(Wo, woT, 512, 512);
    wtrans<<<dim3(64, 16, 4), blk, 0, stream>>>(W1, w1T, 512, 2048);
    wtrans<<<dim3(16, 64, 4), blk, 0, stream>>>(W2, w2T, 2048, 512);
    build_posemb<<<1024, blk, 0, stream>>>(peb);

    build_xcat<<<18432, blk, 0, stream>>>(x, action, act_emb, xcatb);
    gemm_bf<false, false, false><<<dim3(4, 64), blk, 0, stream>>>(xcatb, 576, w1t, 576, nullptr, g32, 512, 8192, 512, 576);
    ln_k<0><<<2048, blk, 0, stream>>>(g32, nullptr, sln1g, sln1b, nullptr, curb, 1e-5f, 1);
    gemm_bf<false, false, false><<<dim3(4, 64), blk, 0, stream>>>(curb, 512, w2t, 512, nullptr, g32, 512, 8192, 512, 512);
    ln_k<0><<<2048, blk, 0, stream>>>(g32, nullptr, sln2g, sln2b, cur32, nullptr, 1e-5f, 0);
    ln_k<0><<<2048, blk, 0, stream>>>(cur32, nullptr, lnfg, lnfb, cur32, curb, 1e-6f, 0);

    for (int l = 0; l < 4; ++l) {
        const ushort* wqkvT_l = wqkvT + (size_t)l * 786432;
        convk<<<4096, blk, 0, stream>>>(mems + (size_t)l * 4194304, memsb);
        gemm_bf<false, false, true><<<dim3(4, 64), blk, 0, stream>>>(curb, 512, wqkvT_l, 512, nullptr, qb, 512, 8192, 512, 512);
        gemm_bf<false, false, true><<<dim3(8, 64), blk, 0, stream>>>(memsb, 512, wqkvT_l + 262144, 512, nullptr, kvb, 1024, 8192, 1024, 512);
        gemm_bf<false, false, true><<<dim3(8, 64), blk, 0, stream>>>(curb, 512, wqkvT_l + 262144, 512, nullptr, kvb + (size_t)8192 * 1024, 1024, 8192, 1024, 512);
        gemm_bf<false, false, true><<<dim3(4, 4), blk, 0, stream>>>(peb, 512, wrT + (size_t)l * 262144, 512, nullptr, rb, 512, 512, 512, 512);
        attn_mfma<<<512, dim3(512), 0, stream>>>(qb, kvb, rb, ub, vb, h1b);
        gemm_bf<false, false, false><<<dim3(4, 64), blk, 0, stream>>>(h1b, 512, woT + (size_t)l * 262144, 512, nullptr, g32, 512, 8192, 512, 512);
        ln_k<1><<<2048, blk, 0, stream>>>(g32, cur32, ln1g + l * 512, ln1b + l * 512, nullptr, h1b, 1e-5f, 0);
        gemm_bf<true, true, true><<<dim3(16, 64), blk, 0, stream>>>(h1b, 512, w1T + (size_t)l * 1048576, 512, b1 + l * 2048, ff1b, 2048, 8192, 2048, 512);
        gemm_bf<true, false, false><<<dim3(4, 64), blk, 0, stream>>>(ff1b, 2048, w2T + (size_t)l * 1048576, 2048, b2 + l * 512, g32, 512, 8192, 512, 2048);
        ln_k<2><<<2048, blk, 0, stream>>>(g32, h1b, ln2g + l * 512, ln2b + l * 512, cur32, curb, 1e-5f, 0);
    }
    final_out<<<16384, blk, 0, stream>>>(cur32, out);
}

// Round 4
// 1024.371 us; speedup vs baseline: 6.7222x; 1.0290x over previous
//
#include <hip/hip_runtime.h>

// TransformerXL forward, MI355X. Round 4: BK=64 swizzled GEMM, fused QKV,
// bf16 bounce epilogue, conflict-free attn V^T staging.
// L=256, KLEN=512, B=32, E=512, H=8, D=64, FF=2048, NL=4.

typedef __attribute__((ext_vector_type(8))) short bf8_t;   // 8 bf16 in 4 VGPRs
typedef __attribute__((ext_vector_type(4))) float f4_t;

__device__ __forceinline__ ushort f2bf(float f) {          // RNE f32->bf16
    uint u = __float_as_uint(f);
    u += 0x7FFFu + ((u >> 16) & 1u);
    return (ushort)(u >> 16);
}
__device__ __forceinline__ float b2f(ushort h) {
    return __uint_as_float(((uint)h) << 16);
}
__device__ __forceinline__ void gload16(const void* g, void* l) {
    __builtin_amdgcn_global_load_lds((const __attribute__((address_space(1))) void*)g,
                                     (__attribute__((address_space(3))) void*)l, 16, 0, 0);
}

// ------------------------------------------------------------ MFMA GEMM bf16
// C[M,N] = A[M,K] @ Bt[N,K]^T (+bias)(+relu). 128x128 tile, BK=64, 256 thr.
// LDS tiles XOR-swizzled: LDS[row][chunk] holds global chunk (chunk^(row&7));
// gload_lds dest stays linear, global src pre-swizzled (both-sides rule).
// M%128==0, N%128==0, K%64==0, lda/ldb multiples of 8.
template<bool BIAS, bool RELU, bool OUTBF>
__global__ __launch_bounds__(256)
void gemm_bf(const ushort* __restrict__ A, int lda,
             const ushort* __restrict__ Bt, int ldb,
             const float* __restrict__ bias,
             void* __restrict__ Cp, int ldc,
             int M, int N, int K)
{
    __shared__ __align__(16) ushort sh[17408];   // 34816 B: staging 32KB / epi [128][136]
    ushort* As = sh;             // [128][64] (chunk-swizzled)
    ushort* Bs = sh + 8192;
    const int t = threadIdx.x;
    const int w = t >> 6, lane = t & 63;
    const int wr = w >> 1, wc = w & 1;
    const int lr = lane >> 4, lc = lane & 15;
    const int m0 = blockIdx.y * 128, n0 = blockIdx.x * 128;

    // staging: call c covers rows c*32 + w*8 + (lane>>3); chunk (lane&7)
    const int srow = w * 8 + (lane >> 3);
    const int gchunk = (lane & 7) ^ (srow & 7);      // pre-swizzled global chunk
    const ushort* Ag = A + (size_t)(m0 + srow) * lda + gchunk * 8;
    const ushort* Bg = Bt + (size_t)(n0 + srow) * ldb + gchunk * 8;
    ushort* Asw = As + w * 512;                      // (w*8 rows)*64
    ushort* Bsw = Bs + w * 512;

    f4_t acc[4][4];
#pragma unroll
    for (int i = 0; i < 4; ++i)
#pragma unroll
        for (int j = 0; j < 4; ++j) acc[i][j] = (f4_t){0.f, 0.f, 0.f, 0.f};

    for (int k0 = 0; k0 < K; k0 += 64) {
#pragma unroll
        for (int c = 0; c < 4; ++c) {
            gload16(Ag + (size_t)c * 32 * lda, Asw + c * 2048);
            gload16(Bg + (size_t)c * 32 * ldb, Bsw + c * 2048);
        }
        Ag += 64; Bg += 64;
        __syncthreads();
#pragma unroll
        for (int kk = 0; kk < 2; ++kk) {
            bf8_t av[4], bv[4];
#pragma unroll
            for (int i = 0; i < 4; ++i) {
                const int row = wr * 64 + i * 16 + lc;
                const int ch = (kk * 4 + lr) ^ (row & 7);
                av[i] = *(const bf8_t*)(As + row * 64 + ch * 8);
            }
#pragma unroll
            for (int j = 0; j < 4; ++j) {
                const int row = wc * 64 + j * 16 + lc;
                const int ch = (kk * 4 + lr) ^ (row & 7);
                bv[j] = *(const bf8_t*)(Bs + row * 64 + ch * 8);
            }
#pragma unroll
            for (int i = 0; i < 4; ++i)
#pragma unroll
                for (int j = 0; j < 4; ++j)
                    acc[i][j] = __builtin_amdgcn_mfma_f32_16x16x32_bf16(av[i], bv[j], acc[i][j], 0, 0, 0);
        }
        __syncthreads();
    }
    // C/D layout: col = lane&15, row = (lane>>4)*4 + reg
    const int crow = wr * 64 + lr * 4;
    const int ccol = wc * 64 + lc;
    if (OUTBF) {
        // bounce through LDS for coalesced 16B bf16 stores
        ushort* Cs = sh;   // [128][136]
#pragma unroll
        for (int i = 0; i < 4; ++i)
#pragma unroll
            for (int j = 0; j < 4; ++j) {
                float bb = BIAS ? bias[n0 + ccol + j * 16] : 0.f;
                f4_t v = acc[i][j];
#pragma unroll
                for (int r = 0; r < 4; ++r) {
                    float o = v[r] + bb;
                    if (RELU) o = fmaxf(o, 0.f);
                    Cs[(crow + i * 16 + r) * 136 + ccol + j * 16] = f2bf(o);
                }
            }
        __syncthreads();
        const int orow = t >> 1, oc0 = (t & 1) * 64;
        ushort* dst = (ushort*)Cp + (size_t)(m0 + orow) * ldc + n0 + oc0;
#pragma unroll
        for (int u = 0; u < 8; ++u)
            *(bf8_t*)(dst + u * 8) = *(const bf8_t*)(Cs + orow * 136 + oc0 + u * 8);
    } else {
        float* C = (float*)Cp;
#pragma unroll
        for (int i = 0; i < 4; ++i)
#pragma unroll
            for (int j = 0; j < 4; ++j) {
                const int col = n0 + ccol + j * 16;
                float bb = BIAS ? bias[col] : 0.f;
                f4_t v = acc[i][j];
#pragma unroll
                for (int r = 0; r < 4; ++r) {
                    float o = v[r] + bb;
                    if (RELU) o = fmaxf(o, 0.f);
                    C[(size_t)(m0 + crow + i * 16 + r) * ldc + col] = o;
                }
            }
    }
}

// ---------------------------------------------------------------- LayerNorm
template<int RMODE>
__global__ __launch_bounds__(256)
void ln_k(const float* __restrict__ X, const void* __restrict__ Rp,
          const float* __restrict__ g, const float* __restrict__ bt,
          float* __restrict__ Yf, ushort* __restrict__ Yb,
          float eps, int do_relu)
{
    const int row  = blockIdx.x * 4 + (threadIdx.x >> 6);
    const int lane = threadIdx.x & 63;
    const float* xp = X + (size_t)row * 512 + lane * 8;
    float4 x0 = *(const float4*)xp, x1 = *(const float4*)(xp + 4);
    float v[8] = {x0.x, x0.y, x0.z, x0.w, x1.x, x1.y, x1.z, x1.w};
    if (RMODE == 1) {
        const float* rp = (const float*)Rp + (size_t)row * 512 + lane * 8;
        float4 r0 = *(const float4*)rp, r1 = *(const float4*)(rp + 4);
        v[0] += r0.x; v[1] += r0.y; v[2] += r0.z; v[3] += r0.w;
        v[4] += r1.x; v[5] += r1.y; v[6] += r1.z; v[7] += r1.w;
    } else if (RMODE == 2) {
        const ushort* rp = (const ushort*)Rp + (size_t)row * 512 + lane * 8;
        ushort4 r0 = *(const ushort4*)rp, r1 = *(const ushort4*)(rp + 4);
        v[0] += b2f(r0.x); v[1] += b2f(r0.y); v[2] += b2f(r0.z); v[3] += b2f(r0.w);
        v[4] += b2f(r1.x); v[5] += b2f(r1.y); v[6] += b2f(r1.z); v[7] += b2f(r1.w);
    }
    float s = 0.f;
#pragma unroll
    for (int i = 0; i < 8; ++i) s += v[i];
#pragma unroll
    for (int m = 1; m < 64; m <<= 1) s += __shfl_xor(s, m);
    float mean = s * (1.f / 512.f);
    float q = 0.f;
#pragma unroll
    for (int i = 0; i < 8; ++i) { float d = v[i] - mean; q = fmaf(d, d, q); }
#pragma unroll
    for (int m = 1; m < 64; m <<= 1) q += __shfl_xor(q, m);
    float rstd = rsqrtf(q * (1.f / 512.f) + eps);
    float4 g0 = *(const float4*)(g + lane * 8), g1 = *(const float4*)(g + lane * 8 + 4);
    float4 c0 = *(const float4*)(bt + lane * 8), c1 = *(const float4*)(bt + lane * 8 + 4);
    float gv[8] = {g0.x, g0.y, g0.z, g0.w, g1.x, g1.y, g1.z, g1.w};
    float bv[8] = {c0.x, c0.y, c0.z, c0.w, c1.x, c1.y, c1.z, c1.w};
    float o[8];
#pragma unroll
    for (int i = 0; i < 8; ++i) {
        o[i] = (v[i] - mean) * rstd * gv[i] + bv[i];
        if (do_relu) o[i] = fmaxf(o[i], 0.f);
    }
    if (Yf) {
        float* yp = Yf + (size_t)row * 512 + lane * 8;
        *(float4*)yp       = make_float4(o[0], o[1], o[2], o[3]);
        *(float4*)(yp + 4) = make_float4(o[4], o[5], o[6], o[7]);
    }
    if (Yb) {
        ushort* yp = Yb + (size_t)row * 512 + lane * 8;
        ushort4 w0, w1;
        w0.x = f2bf(o[0]); w0.y = f2bf(o[1]); w0.z = f2bf(o[2]); w0.w = f2bf(o[3]);
        w1.x = f2bf(o[4]); w1.y = f2bf(o[5]); w1.z = f2bf(o[6]); w1.w = f2bf(o[7]);
        *(ushort4*)yp       = w0;
        *(ushort4*)(yp + 4) = w1;
    }
}

// ---------------------------------------------- weight transpose+cast f32->bf16
__global__ __launch_bounds__(256)
void wtrans(const float* __restrict__ in, ushort* __restrict__ out, int K, int N)
{
    __shared__ float tl[32][33];
    const size_t bo = (size_t)blockIdx.z * K * N;
    in += bo; out += bo;
    const int k0 = blockIdx.y * 32, n0 = blockIdx.x * 32;
    const int tx = threadIdx.x & 31, ty = threadIdx.x >> 5;
    for (int i = ty; i < 32; i += 8) tl[i][tx] = in[(size_t)(k0 + i) * N + n0 + tx];
    __syncthreads();
    for (int i = ty; i < 32; i += 8) out[(size_t)(n0 + i) * K + k0 + tx] = f2bf(tl[tx][i]);
}

__global__ void convk(const float* __restrict__ in, ushort* __restrict__ out)
{
    int i = (blockIdx.x * 256 + threadIdx.x) * 4;
    float4 v = *(const float4*)(in + i);
    ushort4 o;
    o.x = f2bf(v.x); o.y = f2bf(v.y); o.z = f2bf(v.z); o.w = f2bf(v.w);
    *(ushort4*)(out + i) = o;
}

// ----------------------------------------------------- stem concat [x | act]
__global__ void build_xcat(const float* __restrict__ x, const int* __restrict__ action,
                           const float* __restrict__ act_emb, ushort* __restrict__ xcat)
{
    int idx = blockIdx.x * 256 + threadIdx.x;           // 8192*576
    int n = idx / 576, e = idx - n * 576;
    int l = n >> 5, b = n & 31;
    float v;
    if (e < 512) v = x[((size_t)b * 256 + l) * 512 + e];
    else         v = act_emb[action[b * 32 + (l >> 3)] * 64 + (e - 512)];
    xcat[idx] = f2bf(v);
}

// ------------------------------------------------- sinusoidal pos embedding
__global__ void build_posemb(ushort* __restrict__ pe)
{
    int idx = blockIdx.x * 256 + threadIdx.x;           // 512*512
    int j = idx >> 9, c = idx & 511;
    float pf = (float)(511 - j);
    int i2 = (c < 256) ? c : c - 256;
    float inv = expf(-(float)i2 * 0.03597789207803197f);
    float ang = pf * inv;
    pe[idx] = f2bf((c < 256) ? sinf(ang) : cosf(ang));
}

// --------------------------------------------------- MFMA flash attention
// block = (b*8+h)*2 + ihalf; 512 thr = 8 waves, wave w owns q-rows iw..iw+15.
// K/V sources split: j<256 from kvm [8192][1024]; j>=256 from qkv [8192][1536].
__global__ __launch_bounds__(512)
void attn_mfma(const ushort* __restrict__ qkv,  // [256*32][1536]  q|k|v
               const ushort* __restrict__ kvm,  // [256*32][1024]  k|v (mems)
               const ushort* __restrict__ rb,   // [512][512]
               const float* __restrict__ ub, const float* __restrict__ vb,
               ushort* __restrict__ ao)         // [256*32][512]
{
    __shared__ __align__(16) ushort Ks[64][72];     // K tile  [j][d]
    __shared__ __align__(16) ushort Vs[64][72];     // V^T tile [d][j]
    __shared__ __align__(16) ushort Rs[192][72];    // r band
    __shared__ __align__(16) ushort Ps[8][16][72];  // per-wave P / O bounce
    const int t = threadIdx.x;
    const int wv = t >> 6, lane = t & 63;
    const int lc = lane & 15, lr = lane >> 4;
    const int bh = (int)blockIdx.x >> 1, ihalf = blockIdx.x & 1;
    const int b = bh >> 3, h = bh & 7;
    const int i0 = ihalf << 7;
    const int iw = i0 + wv * 16;

    bf8_t au[2], aw[2];
#pragma unroll
    for (int kk = 0; kk < 2; ++kk) {
        const ushort* qp = qkv + ((size_t)(iw + lc) * 32 + b) * 1536 + h * 64 + kk * 32 + lr * 8;
        bf8_t q8 = *(const bf8_t*)qp;
        const float* up = ub + h * 64 + kk * 32 + lr * 8;
        const float* vp = vb + h * 64 + kk * 32 + lr * 8;
#pragma unroll
        for (int e = 0; e < 8; ++e) {
            float qf = b2f((ushort)q8[e]);
            au[kk][e] = (short)f2bf(qf + up[e]);
            aw[kk][e] = (short)f2bf(qf + vp[e]);
        }
    }

    f4_t o[4];
#pragma unroll
    for (int d = 0; d < 4; ++d) o[d] = (f4_t){0.f, 0.f, 0.f, 0.f};
    float mrun[4] = {-3.0e38f, -3.0e38f, -3.0e38f, -3.0e38f};
    float lrun[4] = {0.f, 0.f, 0.f, 0.f};

    const int njt = ihalf ? 8 : 6;
    for (int jt = 0; jt < njt; ++jt) {
        const int j0 = jt << 6;
        const bool in_mem = j0 < 256;
        __syncthreads();
        {   // ---- cooperative staging ----
            const int jl = t >> 3, d0 = (t & 7) * 8;
            const ushort* kp = in_mem
                ? kvm + ((size_t)(j0 + jl) * 32 + b) * 1024 + h * 64 + d0
                : qkv + ((size_t)(j0 - 256 + jl) * 32 + b) * 1536 + 512 + h * 64 + d0;
            *(bf8_t*)&Ks[jl][d0] = *(const bf8_t*)kp;
            // V^T: wave wv covers j-slab j0+wv*8..+7; lane = d. 2B-coalesced
            // global reads (64 lanes = 128B row), then one b128 LDS write.
            bf8_t vv;
#pragma unroll
            for (int e = 0; e < 8; ++e) {
                const int jj = j0 + wv * 8 + e;
                vv[e] = (short)(in_mem
                    ? kvm[((size_t)jj * 32 + b) * 1024 + 512 + h * 64 + lane]
                    : qkv[((size_t)(jj - 256) * 32 + b) * 1536 + 1024 + h * 64 + lane]);
            }
            *(bf8_t*)&Vs[lane][wv * 8] = vv;
            const int rbase0 = j0 - i0 + 128;
#pragma unroll
            for (int p = 0; p < 3; ++p) {
                const int rr = p * 64 + jl;
                const int jr = min(rbase0 + rr, 511);
                *(bf8_t*)&Rs[rr][d0] = *(const bf8_t*)(rb + (size_t)jr * 512 + h * 64 + d0);
            }
        }
        __syncthreads();
        if (j0 <= iw + 271) {
            f4_t acf[4], bdf[5];
#pragma unroll
            for (int jj = 0; jj < 4; ++jj) acf[jj] = (f4_t){0.f, 0.f, 0.f, 0.f};
#pragma unroll
            for (int fj = 0; fj < 5; ++fj) bdf[fj] = (f4_t){0.f, 0.f, 0.f, 0.f};
#pragma unroll
            for (int jj = 0; jj < 4; ++jj)
#pragma unroll
                for (int kk = 0; kk < 2; ++kk) {
                    bf8_t kf = *(const bf8_t*)&Ks[jj * 16 + lc][kk * 32 + lr * 8];
                    acf[jj] = __builtin_amdgcn_mfma_f32_16x16x32_bf16(au[kk], kf, acf[jj], 0, 0, 0);
                }
            const int rboff = 112 - wv * 16;
#pragma unroll
            for (int fj = 0; fj < 5; ++fj)
#pragma unroll
                for (int kk = 0; kk < 2; ++kk) {
                    bf8_t rf = *(const bf8_t*)&Rs[rboff + fj * 16 + lc][kk * 32 + lr * 8];
                    bdf[fj] = __builtin_amdgcn_mfma_f32_16x16x32_bf16(aw[kk], rf, bdf[fj], 0, 0, 0);
                }
            float pm[4][4];
            float mt[4] = {-3.0e38f, -3.0e38f, -3.0e38f, -3.0e38f};
            const int jbase = j0 + lc - iw - 256;
#pragma unroll
            for (int jj = 0; jj < 4; ++jj)
#pragma unroll
                for (int rg = 0; rg < 4; ++rg) {
                    const int il = lr * 4 + rg;
                    const int srcl = (lane & 48) | ((lc + 15 - il) & 15);
                    float lo = __shfl(bdf[jj][rg], srcl, 64);
                    float hi = __shfl(bdf[jj + 1][rg], srcl, 64);
                    float bd = (lc > il) ? hi : lo;
                    float s = (acf[jj][rg] + bd) * 0.125f;
                    if (jbase + jj * 16 > il) s = -1e30f;
                    pm[jj][rg] = s;
                    mt[rg] = fmaxf(mt[rg], s);
                }
            float corr[4];
#pragma unroll
            for (int rg = 0; rg < 4; ++rg) {
#pragma unroll
                for (int mm = 1; mm < 16; mm <<= 1)
                    mt[rg] = fmaxf(mt[rg], __shfl_xor(mt[rg], mm, 64));
                float mnew = fmaxf(mrun[rg], mt[rg]);
                corr[rg] = __expf(mrun[rg] - mnew);
                mrun[rg] = mnew;
            }
            float ps4[4] = {0.f, 0.f, 0.f, 0.f};
#pragma unroll
            for (int jj = 0; jj < 4; ++jj)
#pragma unroll
                for (int rg = 0; rg < 4; ++rg) {
                    float p = __expf(pm[jj][rg] - mrun[rg]);
                    ps4[rg] += p;
                    Ps[wv][lr * 4 + rg][jj * 16 + lc] = f2bf(p);
                }
#pragma unroll
            for (int rg = 0; rg < 4; ++rg) {
#pragma unroll
                for (int mm = 1; mm < 16; mm <<= 1)
                    ps4[rg] += __shfl_xor(ps4[rg], mm, 64);
                lrun[rg] = lrun[rg] * corr[rg] + ps4[rg];
            }
            float c0 = __shfl(corr[0], (lc >> 2) << 4, 64);
            float c1 = __shfl(corr[1], (lc >> 2) << 4, 64);
            float c2 = __shfl(corr[2], (lc >> 2) << 4, 64);
            float c3 = __shfl(corr[3], (lc >> 2) << 4, 64);
            float myc = (lc & 2) ? ((lc & 1) ? c3 : c2) : ((lc & 1) ? c1 : c0);
#pragma unroll
            for (int db = 0; db < 4; ++db)
#pragma unroll
                for (int rg = 0; rg < 4; ++rg) o[db][rg] *= myc;
#pragma unroll
            for (int kb = 0; kb < 2; ++kb) {
                bf8_t pf = *(const bf8_t*)&Ps[wv][lc][kb * 32 + lr * 8];
#pragma unroll
                for (int db = 0; db < 4; ++db) {
                    bf8_t vf = *(const bf8_t*)&Vs[db * 16 + lc][kb * 32 + lr * 8];
                    o[db] = __builtin_amdgcn_mfma_f32_16x16x32_bf16(vf, pf, o[db], 0, 0, 0);
                }
            }
        }
    }
    float i4[4];
#pragma unroll
    for (int rg = 0; rg < 4; ++rg) i4[rg] = 1.f / lrun[rg];
    float s0 = __shfl(i4[0], (lc >> 2) << 4, 64);
    float s1 = __shfl(i4[1], (lc >> 2) << 4, 64);
    float s2 = __shfl(i4[2], (lc >> 2) << 4, 64);
    float s3 = __shfl(i4[3], (lc >> 2) << 4, 64);
    float myi = (lc & 2) ? ((lc & 1) ? s3 : s2) : ((lc & 1) ? s1 : s0);
#pragma unroll
    for (int db = 0; db < 4; ++db)
#pragma unroll
        for (int rg = 0; rg < 4; ++rg)
            Ps[wv][lc][db * 16 + lr * 4 + rg] = f2bf(o[db][rg] * myi);
    const int il2 = lane >> 2, dsg = (lane & 3) << 4;
    bf8_t e0 = *(const bf8_t*)&Ps[wv][il2][dsg];
    bf8_t e1 = *(const bf8_t*)&Ps[wv][il2][dsg + 8];
    ushort* dst = ao + ((size_t)(iw + il2) * 32 + b) * 512 + h * 64 + dsg;
    *(bf8_t*)dst = e0;
    *(bf8_t*)(dst + 8) = e1;
}

// ------------------------------------------------------------ final transpose
__global__ void final_out(const float* __restrict__ cur, float* __restrict__ out)
{
    int idx = blockIdx.x * 256 + threadIdx.x;   // 8192*512
    int n = idx >> 9, e = idx & 511;
    int l = n >> 5, b = n & 31;
    out[((size_t)b * 256 + l) * 512 + e] = cur[idx];
}

// ---------------------------------------------------------------------------
extern "C" void kernel_launch(void* const* d_in, const int* in_sizes, int n_in,
                              void* d_out, int out_size, void* d_ws, size_t ws_size,
                              hipStream_t stream)
{
    const float* x       = (const float*)d_in[0];
    const int*   action  = (const int*)d_in[1];
    const float* mems    = (const float*)d_in[4];
    const float* act_emb = (const float*)d_in[5];
    const float* stem_w1 = (const float*)d_in[6];
    const float* sln1g   = (const float*)d_in[7];
    const float* sln1b   = (const float*)d_in[8];
    const float* stem_w2 = (const float*)d_in[9];
    const float* sln2g   = (const float*)d_in[10];
    const float* sln2b   = (const float*)d_in[11];
    const float* lnfg    = (const float*)d_in[12];
    const float* lnfb    = (const float*)d_in[13];
    const float* ub      = (const float*)d_in[14];
    const float* vb      = (const float*)d_in[15];
    const float* Wqkv    = (const float*)d_in[16];
    const float* Wr      = (const float*)d_in[17];
    const float* Wo      = (const float*)d_in[18];
    const float* ln1g    = (const float*)d_in[19];
    const float* ln1b    = (const float*)d_in[20];
    const float* W1      = (const float*)d_in[21];
    const float* b1      = (const float*)d_in[22];
    const float* W2      = (const float*)d_in[23];
    const float* b2      = (const float*)d_in[24];
    const float* ln2g    = (const float*)d_in[25];
    const float* ln2b    = (const float*)d_in[26];
    float* out = (float*)d_out;

    // ---- workspace layout (bytes), total ~116.1 MB ----
    char* W = (char*)d_ws;
    float*  cur32 = (float*) (W + 0);           // 16 MB residual f32
    float*  g32   = (float*) (W + 16777216);    // 16 MB gemm f32 scratch (hosts memsb)
    ushort* curb  = (ushort*)(W + 33554432);    //  8 MB cur bf16
    ushort* h1b   = (ushort*)(W + 41943040);    //  8 MB h1/ao bf16
    ushort* qkvb  = (ushort*)(W + 50331648);    // 24 MB qkv [8192][1536]
    ushort* kvm   = (ushort*)(W + 75497472);    // 16 MB kv mems [8192][1024]
    ushort* rbuf  = (ushort*)(W + 92274688);    // 512 KB
    ushort* peb   = (ushort*)(W + 92798976);    // 512 KB
    ushort* wts   = (ushort*)(W + 93323264);    // 27 MB transposed bf16 weights
    ushort* xcatb = qkvb;                       // stem alias (dead before qkv use)
    ushort* ff1b  = qkvb;                       // FF1 alias (qkv+kvm dead post-attn)
    ushort* memsb = (ushort*)g32;               // 8 MB alias (g32 dead at layer start)
    ushort* w1t    = wts;                       // [512][576]
    ushort* w2t    = wts + 294912;              // [512][512]
    ushort* wqkvT  = wts + 557056;              // [4][1536][512]
    ushort* wrT    = wts + 3702784;             // [4][512][512]
    ushort* woT    = wts + 4751360;             // [4][512][512]
    ushort* w1T    = wts + 5799936;             // [4][2048][512]
    ushort* w2T    = wts + 9994240;             // [4][512][2048]

    dim3 blk(256);
    wtrans<<<dim3(16, 18, 1), blk, 0, stream>>>(stem_w1, w1t, 576, 512);
    wtrans<<<dim3(16, 16, 1), blk, 0, stream>>>(stem_w2, w2t, 512, 512);
    wtrans<<<dim3(48, 16, 4), blk, 0, stream>>>(Wqkv, wqkvT, 512, 1536);
    wtrans<<<dim3(16, 16, 4), blk, 0, stream>>>(Wr, wrT, 512, 512);
    wtrans<<<dim3(16, 16, 4), blk, 0, stream>>>(Wo, woT, 512, 512);
    wtrans<<<dim3(64, 16, 4), blk, 0, stream>>>(W1, w1T, 512, 2048);
    wtrans<<<dim3(16, 64, 4), blk, 0, stream>>>(W2, w2T, 2048, 512);
    build_posemb<<<1024, blk, 0, stream>>>(peb);

    build_xcat<<<18432, blk, 0, stream>>>(x, action, act_emb, xcatb);
    gemm_bf<false, false, false><<<dim3(4, 64), blk, 0, stream>>>(xcatb, 576, w1t, 576, nullptr, g32, 512, 8192, 512, 576);
    ln_k<0><<<2048, blk, 0, stream>>>(g32, nullptr, sln1g, sln1b, nullptr, curb, 1e-5f, 1);
    gemm_bf<false, false, false><<<dim3(4, 64), blk, 0, stream>>>(curb, 512, w2t, 512, nullptr, g32, 512, 8192, 512, 512);
    ln_k<0><<<2048, blk, 0, stream>>>(g32, nullptr, sln2g, sln2b, cur32, nullptr, 1e-5f, 0);
    ln_k<0><<<2048, blk, 0, stream>>>(cur32, nullptr, lnfg, lnfb, cur32, curb, 1e-6f, 0);

    for (int l = 0; l < 4; ++l) {
        const ushort* wqkvT_l = wqkvT + (size_t)l * 786432;
        convk<<<4096, blk, 0, stream>>>(mems + (size_t)l * 4194304, memsb);
        // fused q|k|v for current tokens: [8192][1536]
        gemm_bf<false, false, true><<<dim3(12, 64), blk, 0, stream>>>(curb, 512, wqkvT_l, 512, nullptr, qkvb, 1536, 8192, 1536, 512);
        // k|v for memory tokens: [8192][1024]
        gemm_bf<false, false, true><<<dim3(8, 64), blk, 0, stream>>>(memsb, 512, wqkvT_l + 262144, 512, nullptr, kvm, 1024, 8192, 1024, 512);
        gemm_bf<false, false, true><<<dim3(4, 4), blk, 0, stream>>>(peb, 512, wrT + (size_t)l * 262144, 512, nullptr, rbuf, 512, 512, 512, 512);
        attn_mfma<<<512, dim3(512), 0, stream>>>(qkvb, kvm, rbuf, ub, vb, h1b);
        gemm_bf<false, false, false><<<dim3(4, 64), blk, 0, stream>>>(h1b, 512, woT + (size_t)l * 262144, 512, nullptr, g32, 512, 8192, 512, 512);
        ln_k<1><<<2048, blk, 0, stream>>>(g32, cur32, ln1g + l * 512, ln1b + l * 512, nullptr, h1b, 1e-5f, 0);
        gemm_bf<true, true, true><<<dim3(16, 64), blk, 0, stream>>>(h1b, 512, w1T + (size_t)l * 1048576, 512, b1 + l * 2048, ff1b, 2048, 8192, 2048, 512);
        gemm_bf<true, false, false><<<dim3(4, 64), blk, 0, stream>>>(ff1b, 2048, w2T + (size_t)l * 1048576, 2048, b2 + l * 512, g32, 512, 8192, 512, 2048);
        ln_k<2><<<2048, blk, 0, stream>>>(g32, h1b, ln2g + l * 512, ln2b + l * 512, cur32, curb, 1e-5f, 0);
    }
    final_out<<<16384, blk, 0, stream>>>(cur32, out);
}

// Round 5
// 995.918 us; speedup vs baseline: 6.9142x; 1.0286x over previous
//
#include <hip/hip_runtime.h>

// TransformerXL forward, MI355X. Round 5: attn = r3 staging + hoisted shuffles
// + rolling R band; fused stem LN-LN; final transpose folded into last LN.
// L=256, KLEN=512, B=32, E=512, H=8, D=64, FF=2048, NL=4.

typedef __attribute__((ext_vector_type(8))) short bf8_t;   // 8 bf16 in 4 VGPRs
typedef __attribute__((ext_vector_type(4))) float f4_t;

__device__ __forceinline__ ushort f2bf(float f) {          // RNE f32->bf16
    uint u = __float_as_uint(f);
    u += 0x7FFFu + ((u >> 16) & 1u);
    return (ushort)(u >> 16);
}
__device__ __forceinline__ float b2f(ushort h) {
    return __uint_as_float(((uint)h) << 16);
}
__device__ __forceinline__ void gload16(const void* g, void* l) {
    __builtin_amdgcn_global_load_lds((const __attribute__((address_space(1))) void*)g,
                                     (__attribute__((address_space(3))) void*)l, 16, 0, 0);
}

// ------------------------------------------------------------ MFMA GEMM bf16
// C[M,N] = A[M,K] @ Bt[N,K]^T (+bias)(+relu). 128x128 tile, BK=64, 256 thr.
// LDS tiles XOR-swizzled via pre-swizzled global source (both-sides rule).
template<bool BIAS, bool RELU, bool OUTBF>
__global__ __launch_bounds__(256)
void gemm_bf(const ushort* __restrict__ A, int lda,
             const ushort* __restrict__ Bt, int ldb,
             const float* __restrict__ bias,
             void* __restrict__ Cp, int ldc,
             int M, int N, int K)
{
    __shared__ __align__(16) ushort sh[17408];   // staging 32KB / epi [128][136]
    ushort* As = sh;             // [128][64] (chunk-swizzled)
    ushort* Bs = sh + 8192;
    const int t = threadIdx.x;
    const int w = t >> 6, lane = t & 63;
    const int wr = w >> 1, wc = w & 1;
    const int lr = lane >> 4, lc = lane & 15;
    const int m0 = blockIdx.y * 128, n0 = blockIdx.x * 128;

    const int srow = w * 8 + (lane >> 3);
    const int gchunk = (lane & 7) ^ (srow & 7);
    const ushort* Ag = A + (size_t)(m0 + srow) * lda + gchunk * 8;
    const ushort* Bg = Bt + (size_t)(n0 + srow) * ldb + gchunk * 8;
    ushort* Asw = As + w * 512;
    ushort* Bsw = Bs + w * 512;

    f4_t acc[4][4];
#pragma unroll
    for (int i = 0; i < 4; ++i)
#pragma unroll
        for (int j = 0; j < 4; ++j) acc[i][j] = (f4_t){0.f, 0.f, 0.f, 0.f};

    for (int k0 = 0; k0 < K; k0 += 64) {
#pragma unroll
        for (int c = 0; c < 4; ++c) {
            gload16(Ag + (size_t)c * 32 * lda, Asw + c * 2048);
            gload16(Bg + (size_t)c * 32 * ldb, Bsw + c * 2048);
        }
        Ag += 64; Bg += 64;
        __syncthreads();
#pragma unroll
        for (int kk = 0; kk < 2; ++kk) {
            bf8_t av[4], bv[4];
#pragma unroll
            for (int i = 0; i < 4; ++i) {
                const int row = wr * 64 + i * 16 + lc;
                const int ch = (kk * 4 + lr) ^ (row & 7);
                av[i] = *(const bf8_t*)(As + row * 64 + ch * 8);
            }
#pragma unroll
            for (int j = 0; j < 4; ++j) {
                const int row = wc * 64 + j * 16 + lc;
                const int ch = (kk * 4 + lr) ^ (row & 7);
                bv[j] = *(const bf8_t*)(Bs + row * 64 + ch * 8);
            }
#pragma unroll
            for (int i = 0; i < 4; ++i)
#pragma unroll
                for (int j = 0; j < 4; ++j)
                    acc[i][j] = __builtin_amdgcn_mfma_f32_16x16x32_bf16(av[i], bv[j], acc[i][j], 0, 0, 0);
        }
        __syncthreads();
    }
    const int crow = wr * 64 + lr * 4;
    const int ccol = wc * 64 + lc;
    if (OUTBF) {
        ushort* Cs = sh;   // [128][136]
#pragma unroll
        for (int i = 0; i < 4; ++i)
#pragma unroll
            for (int j = 0; j < 4; ++j) {
                float bb = BIAS ? bias[n0 + ccol + j * 16] : 0.f;
                f4_t v = acc[i][j];
#pragma unroll
                for (int r = 0; r < 4; ++r) {
                    float o = v[r] + bb;
                    if (RELU) o = fmaxf(o, 0.f);
                    Cs[(crow + i * 16 + r) * 136 + ccol + j * 16] = f2bf(o);
                }
            }
        __syncthreads();
        const int orow = t >> 1, oc0 = (t & 1) * 64;
        ushort* dst = (ushort*)Cp + (size_t)(m0 + orow) * ldc + n0 + oc0;
#pragma unroll
        for (int u = 0; u < 8; ++u)
            *(bf8_t*)(dst + u * 8) = *(const bf8_t*)(Cs + orow * 136 + oc0 + u * 8);
    } else {
        float* C = (float*)Cp;
#pragma unroll
        for (int i = 0; i < 4; ++i)
#pragma unroll
            for (int j = 0; j < 4; ++j) {
                const int col = n0 + ccol + j * 16;
                float bb = BIAS ? bias[col] : 0.f;
                f4_t v = acc[i][j];
#pragma unroll
                for (int r = 0; r < 4; ++r) {
                    float o = v[r] + bb;
                    if (RELU) o = fmaxf(o, 0.f);
                    C[(size_t)(m0 + crow + i * 16 + r) * ldc + col] = o;
                }
            }
    }
}

// ---------------------------------------------------------------- LayerNorm
// RMODE: 0 none, 1 f32 residual, 2 bf16 residual. TROUT: f32 out transposed
// to [B,L] layout (folds final_out).
template<int RMODE, bool TROUT>
__global__ __launch_bounds__(256)
void ln_k(const float* __restrict__ X, const void* __restrict__ Rp,
          const float* __restrict__ g, const float* __restrict__ bt,
          float* __restrict__ Yf, ushort* __restrict__ Yb,
          float eps, int do_relu)
{
    const int row  = blockIdx.x * 4 + (threadIdx.x >> 6);
    const int lane = threadIdx.x & 63;
    const float* xp = X + (size_t)row * 512 + lane * 8;
    float4 x0 = *(const float4*)xp, x1 = *(const float4*)(xp + 4);
    float v[8] = {x0.x, x0.y, x0.z, x0.w, x1.x, x1.y, x1.z, x1.w};
    if (RMODE == 1) {
        const float* rp = (const float*)Rp + (size_t)row * 512 + lane * 8;
        float4 r0 = *(const float4*)rp, r1 = *(const float4*)(rp + 4);
        v[0] += r0.x; v[1] += r0.y; v[2] += r0.z; v[3] += r0.w;
        v[4] += r1.x; v[5] += r1.y; v[6] += r1.z; v[7] += r1.w;
    } else if (RMODE == 2) {
        const ushort* rp = (const ushort*)Rp + (size_t)row * 512 + lane * 8;
        ushort4 r0 = *(const ushort4*)rp, r1 = *(const ushort4*)(rp + 4);
        v[0] += b2f(r0.x); v[1] += b2f(r0.y); v[2] += b2f(r0.z); v[3] += b2f(r0.w);
        v[4] += b2f(r1.x); v[5] += b2f(r1.y); v[6] += b2f(r1.z); v[7] += b2f(r1.w);
    }
    float s = 0.f;
#pragma unroll
    for (int i = 0; i < 8; ++i) s += v[i];
#pragma unroll
    for (int m = 1; m < 64; m <<= 1) s += __shfl_xor(s, m);
    float mean = s * (1.f / 512.f);
    float q = 0.f;
#pragma unroll
    for (int i = 0; i < 8; ++i) { float d = v[i] - mean; q = fmaf(d, d, q); }
#pragma unroll
    for (int m = 1; m < 64; m <<= 1) q += __shfl_xor(q, m);
    float rstd = rsqrtf(q * (1.f / 512.f) + eps);
    float4 g0 = *(const float4*)(g + lane * 8), g1 = *(const float4*)(g + lane * 8 + 4);
    float4 c0 = *(const float4*)(bt + lane * 8), c1 = *(const float4*)(bt + lane * 8 + 4);
    float gv[8] = {g0.x, g0.y, g0.z, g0.w, g1.x, g1.y, g1.z, g1.w};
    float bv[8] = {c0.x, c0.y, c0.z, c0.w, c1.x, c1.y, c1.z, c1.w};
    float o[8];
#pragma unroll
    for (int i = 0; i < 8; ++i) {
        o[i] = (v[i] - mean) * rstd * gv[i] + bv[i];
        if (do_relu) o[i] = fmaxf(o[i], 0.f);
    }
    if (Yf) {
        float* yp;
        if (TROUT) {
            const int bq = row & 31, lq = row >> 5;
            yp = Yf + ((size_t)bq * 256 + lq) * 512 + lane * 8;
        } else {
            yp = Yf + (size_t)row * 512 + lane * 8;
        }
        *(float4*)yp       = make_float4(o[0], o[1], o[2], o[3]);
        *(float4*)(yp + 4) = make_float4(o[4], o[5], o[6], o[7]);
    }
    if (Yb) {
        ushort* yp = Yb + (size_t)row * 512 + lane * 8;
        ushort4 w0, w1;
        w0.x = f2bf(o[0]); w0.y = f2bf(o[1]); w0.z = f2bf(o[2]); w0.w = f2bf(o[3]);
        w1.x = f2bf(o[4]); w1.y = f2bf(o[5]); w1.z = f2bf(o[6]); w1.w = f2bf(o[7]);
        *(ushort4*)yp       = w0;
        *(ushort4*)(yp + 4) = w1;
    }
}

// ------------------------------------------ fused stem double LN (ln2 -> lnf)
__global__ __launch_bounds__(256)
void ln_stem2(const float* __restrict__ X,
              const float* __restrict__ g1, const float* __restrict__ b1,
              const float* __restrict__ g2, const float* __restrict__ b2,
              float* __restrict__ Yf, ushort* __restrict__ Yb)
{
    const int row  = blockIdx.x * 4 + (threadIdx.x >> 6);
    const int lane = threadIdx.x & 63;
    const float* xp = X + (size_t)row * 512 + lane * 8;
    float4 x0 = *(const float4*)xp, x1 = *(const float4*)(xp + 4);
    float v[8] = {x0.x, x0.y, x0.z, x0.w, x1.x, x1.y, x1.z, x1.w};
    float s = 0.f;
#pragma unroll
    for (int i = 0; i < 8; ++i) s += v[i];
#pragma unroll
    for (int m = 1; m < 64; m <<= 1) s += __shfl_xor(s, m);
    float mean = s * (1.f / 512.f);
    float q = 0.f;
#pragma unroll
    for (int i = 0; i < 8; ++i) { float d = v[i] - mean; q = fmaf(d, d, q); }
#pragma unroll
    for (int m = 1; m < 64; m <<= 1) q += __shfl_xor(q, m);
    float rstd = rsqrtf(q * (1.f / 512.f) + 1e-5f);
#pragma unroll
    for (int i = 0; i < 8; ++i)
        v[i] = (v[i] - mean) * rstd * g1[lane * 8 + i] + b1[lane * 8 + i];
    // second LN (eps 1e-6)
    s = 0.f;
#pragma unroll
    for (int i = 0; i < 8; ++i) s += v[i];
#pragma unroll
    for (int m = 1; m < 64; m <<= 1) s += __shfl_xor(s, m);
    mean = s * (1.f / 512.f);
    q = 0.f;
#pragma unroll
    for (int i = 0; i < 8; ++i) { float d = v[i] - mean; q = fmaf(d, d, q); }
#pragma unroll
    for (int m = 1; m < 64; m <<= 1) q += __shfl_xor(q, m);
    rstd = rsqrtf(q * (1.f / 512.f) + 1e-6f);
    float o[8];
#pragma unroll
    for (int i = 0; i < 8; ++i)
        o[i] = (v[i] - mean) * rstd * g2[lane * 8 + i] + b2[lane * 8 + i];
    float* yp = Yf + (size_t)row * 512 + lane * 8;
    *(float4*)yp       = make_float4(o[0], o[1], o[2], o[3]);
    *(float4*)(yp + 4) = make_float4(o[4], o[5], o[6], o[7]);
    ushort* yb = Yb + (size_t)row * 512 + lane * 8;
    ushort4 w0, w1;
    w0.x = f2bf(o[0]); w0.y = f2bf(o[1]); w0.z = f2bf(o[2]); w0.w = f2bf(o[3]);
    w1.x = f2bf(o[4]); w1.y = f2bf(o[5]); w1.z = f2bf(o[6]); w1.w = f2bf(o[7]);
    *(ushort4*)yb       = w0;
    *(ushort4*)(yb + 4) = w1;
}

// ---------------------------------------------- weight transpose+cast f32->bf16
__global__ __launch_bounds__(256)
void wtrans(const float* __restrict__ in, ushort* __restrict__ out, int K, int N)
{
    __shared__ float tl[32][33];
    const size_t bo = (size_t)blockIdx.z * K * N;
    in += bo; out += bo;
    const int k0 = blockIdx.y * 32, n0 = blockIdx.x * 32;
    const int tx = threadIdx.x & 31, ty = threadIdx.x >> 5;
    for (int i = ty; i < 32; i += 8) tl[i][tx] = in[(size_t)(k0 + i) * N + n0 + tx];
    __syncthreads();
    for (int i = ty; i < 32; i += 8) out[(size_t)(n0 + i) * K + k0 + tx] = f2bf(tl[tx][i]);
}

__global__ void convk(const float* __restrict__ in, ushort* __restrict__ out)
{
    int i = (blockIdx.x * 256 + threadIdx.x) * 4;
    float4 v = *(const float4*)(in + i);
    ushort4 o;
    o.x = f2bf(v.x); o.y = f2bf(v.y); o.z = f2bf(v.z); o.w = f2bf(v.w);
    *(ushort4*)(out + i) = o;
}

// ----------------------------------------------------- stem concat [x | act]
__global__ void build_xcat(const float* __restrict__ x, const int* __restrict__ action,
                           const float* __restrict__ act_emb, ushort* __restrict__ xcat)
{
    int idx = blockIdx.x * 256 + threadIdx.x;           // 8192*576
    int n = idx / 576, e = idx - n * 576;
    int l = n >> 5, b = n & 31;
    float v;
    if (e < 512) v = x[((size_t)b * 256 + l) * 512 + e];
    else         v = act_emb[action[b * 32 + (l >> 3)] * 64 + (e - 512)];
    xcat[idx] = f2bf(v);
}

// ------------------------------------------------- sinusoidal pos embedding
__global__ void build_posemb(ushort* __restrict__ pe)
{
    int idx = blockIdx.x * 256 + threadIdx.x;           // 512*512
    int j = idx >> 9, c = idx & 511;
    float pf = (float)(511 - j);
    int i2 = (c < 256) ? c : c - 256;
    float inv = expf(-(float)i2 * 0.03597789207803197f);
    float ang = pf * inv;
    pe[idx] = f2bf((c < 256) ? sinf(ang) : cosf(ang));
}

// --------------------------------------------------- MFMA flash attention
// block = (b*8+h)*2 + ihalf; 512 thr = 8 waves, wave wv owns q-rows iw..iw+15.
// Sources: j<256 from kvm [8192][1024]; j>=256 from qkv [8192][1536].
// Rs is a rolling 3-slab circular band (shifts by 64 per j-tile).
__global__ __launch_bounds__(512)
void attn_mfma(const ushort* __restrict__ qkv,  // [256*32][1536]  q|k|v
               const ushort* __restrict__ kvm,  // [256*32][1024]  k|v (mems)
               const ushort* __restrict__ rb,   // [512][512]
               const float* __restrict__ ub, const float* __restrict__ vb,
               ushort* __restrict__ ao)         // [256*32][512]
{
    __shared__ __align__(16) ushort Ks[64][72];     // K tile  [j][d]
    __shared__ __align__(16) ushort Vs[64][72];     // V^T tile [d][j]
    __shared__ __align__(16) ushort Rs[192][72];    // rolling r band (3 slabs)
    __shared__ __align__(16) ushort Ps[8][16][72];  // per-wave P / O bounce
    const int t = threadIdx.x;
    const int wv = t >> 6, lane = t & 63;
    const int lc = lane & 15, lr = lane >> 4;
    const int bh = (int)blockIdx.x >> 1, ihalf = blockIdx.x & 1;
    const int b = bh >> 3, h = bh & 7;
    const int i0 = ihalf << 7;
    const int iw = i0 + wv * 16;

    bf8_t au[2], aw[2];
#pragma unroll
    for (int kk = 0; kk < 2; ++kk) {
        const ushort* qp = qkv + ((size_t)(iw + lc) * 32 + b) * 1536 + h * 64 + kk * 32 + lr * 8;
        bf8_t q8 = *(const bf8_t*)qp;
        const float* up = ub + h * 64 + kk * 32 + lr * 8;
        const float* vp = vb + h * 64 + kk * 32 + lr * 8;
#pragma unroll
        for (int e = 0; e < 8; ++e) {
            float qf = b2f((ushort)q8[e]);
            au[kk][e] = (short)f2bf(qf + up[e]);
            aw[kk][e] = (short)f2bf(qf + vp[e]);
        }
    }

    f4_t o[4];
#pragma unroll
    for (int d = 0; d < 4; ++d) o[d] = (f4_t){0.f, 0.f, 0.f, 0.f};
    float mrun[4] = {-3.0e38f, -3.0e38f, -3.0e38f, -3.0e38f};
    float lrun[4] = {0.f, 0.f, 0.f, 0.f};

    const int njt = ihalf ? 8 : 6;
    for (int jt = 0; jt < njt; ++jt) {
        const int j0 = jt << 6;
        const bool in_mem = j0 < 256;
        __syncthreads();
        {   // ---- cooperative staging ----
            const int jl = t >> 3, d0 = (t & 7) * 8;
            const ushort* kp = in_mem
                ? kvm + ((size_t)(j0 + jl) * 32 + b) * 1024 + h * 64 + d0
                : qkv + ((size_t)(j0 - 256 + jl) * 32 + b) * 1536 + 512 + h * 64 + d0;
            *(bf8_t*)&Ks[jl][d0] = *(const bf8_t*)kp;
            // V^T: 16B/lane global reads, scalar LDS scatter (r3 pattern)
            const int vrow = ((t >> 3) & 7) * 8 + wv;
            const ushort* vp = in_mem
                ? kvm + ((size_t)(j0 + vrow) * 32 + b) * 1024 + 512 + h * 64 + d0
                : qkv + ((size_t)(j0 - 256 + vrow) * 32 + b) * 1536 + 1024 + h * 64 + d0;
            bf8_t vv = *(const bf8_t*)vp;
#pragma unroll
            for (int e = 0; e < 8; ++e) Vs[d0 + e][vrow] = (ushort)vv[e];
            // rolling R band: stage slab(s). logical slab s at jt -> phys (jt+s)%3
            const int rbase0 = j0 - i0 + 128;
            if (jt == 0) {
#pragma unroll
                for (int p = 0; p < 3; ++p) {
                    const int jr = min(rbase0 + p * 64 + jl, 511);
                    *(bf8_t*)&Rs[p * 64 + jl][d0] = *(const bf8_t*)(rb + (size_t)jr * 512 + h * 64 + d0);
                }
            } else {
                const int phys = ((jt + 2) % 3) * 64 + jl;
                const int jr = min(rbase0 + 128 + jl, 511);
                *(bf8_t*)&Rs[phys][d0] = *(const bf8_t*)(rb + (size_t)jr * 512 + h * 64 + d0);
            }
        }
        __syncthreads();
        if (j0 <= iw + 271) {
            f4_t acf[4], bdf[5];
#pragma unroll
            for (int jj = 0; jj < 4; ++jj) acf[jj] = (f4_t){0.f, 0.f, 0.f, 0.f};
#pragma unroll
            for (int fj = 0; fj < 5; ++fj) bdf[fj] = (f4_t){0.f, 0.f, 0.f, 0.f};
#pragma unroll
            for (int jj = 0; jj < 4; ++jj)
#pragma unroll
                for (int kk = 0; kk < 2; ++kk) {
                    bf8_t kf = *(const bf8_t*)&Ks[jj * 16 + lc][kk * 32 + lr * 8];
                    acf[jj] = __builtin_amdgcn_mfma_f32_16x16x32_bf16(au[kk], kf, acf[jj], 0, 0, 0);
                }
            const int rboff = 112 - wv * 16;
#pragma unroll
            for (int fj = 0; fj < 5; ++fj) {
                const int lbase = rboff + fj * 16;
                const int prow = ((jt + (lbase >> 6)) % 3) * 64 + (lbase & 63) + lc;
#pragma unroll
                for (int kk = 0; kk < 2; ++kk) {
                    bf8_t rf = *(const bf8_t*)&Rs[prow][kk * 32 + lr * 8];
                    bdf[fj] = __builtin_amdgcn_mfma_f32_16x16x32_bf16(aw[kk], rf, bdf[fj], 0, 0, 0);
                }
            }
            // ---- rel-shift (hoisted shuffles) + mask + online softmax ----
            float pm[4][4];
            float mt[4] = {-3.0e38f, -3.0e38f, -3.0e38f, -3.0e38f};
            const int jbase = j0 + lc - iw - 256;
#pragma unroll
            for (int rg = 0; rg < 4; ++rg) {
                const int il = lr * 4 + rg;
                const int srcl = (lane & 48) | ((lc + 15 - il) & 15);
                float shf[5];
#pragma unroll
                for (int fj = 0; fj < 5; ++fj) shf[fj] = __shfl(bdf[fj][rg], srcl, 64);
#pragma unroll
                for (int jj = 0; jj < 4; ++jj) {
                    float bd = (lc > il) ? shf[jj + 1] : shf[jj];
                    float s = (acf[jj][rg] + bd) * 0.125f;
                    if (jbase + jj * 16 > il) s = -1e30f;
                    pm[jj][rg] = s;
                    mt[rg] = fmaxf(mt[rg], s);
                }
            }
            float corr[4];
#pragma unroll
            for (int rg = 0; rg < 4; ++rg) {
#pragma unroll
                for (int mm = 1; mm < 16; mm <<= 1)
                    mt[rg] = fmaxf(mt[rg], __shfl_xor(mt[rg], mm, 64));
                float mnew = fmaxf(mrun[rg], mt[rg]);
                corr[rg] = __expf(mrun[rg] - mnew);
                mrun[rg] = mnew;
            }
            float ps4[4] = {0.f, 0.f, 0.f, 0.f};
#pragma unroll
            for (int jj = 0; jj < 4; ++jj)
#pragma unroll
                for (int rg = 0; rg < 4; ++rg) {
                    float p = __expf(pm[jj][rg] - mrun[rg]);
                    ps4[rg] += p;
                    Ps[wv][lr * 4 + rg][jj * 16 + lc] = f2bf(p);
                }
#pragma unroll
            for (int rg = 0; rg < 4; ++rg) {
#pragma unroll
                for (int mm = 1; mm < 16; mm <<= 1)
                    ps4[rg] += __shfl_xor(ps4[rg], mm, 64);
                lrun[rg] = lrun[rg] * corr[rg] + ps4[rg];
            }
            float c0 = __shfl(corr[0], (lc >> 2) << 4, 64);
            float c1 = __shfl(corr[1], (lc >> 2) << 4, 64);
            float c2 = __shfl(corr[2], (lc >> 2) << 4, 64);
            float c3 = __shfl(corr[3], (lc >> 2) << 4, 64);
            float myc = (lc & 2) ? ((lc & 1) ? c3 : c2) : ((lc & 1) ? c1 : c0);
#pragma unroll
            for (int db = 0; db < 4; ++db)
#pragma unroll
                for (int rg = 0; rg < 4; ++rg) o[db][rg] *= myc;
#pragma unroll
            for (int kb = 0; kb < 2; ++kb) {
                bf8_t pf = *(const bf8_t*)&Ps[wv][lc][kb * 32 + lr * 8];
#pragma unroll
                for (int db = 0; db < 4; ++db) {
                    bf8_t vf = *(const bf8_t*)&Vs[db * 16 + lc][kb * 32 + lr * 8];
                    o[db] = __builtin_amdgcn_mfma_f32_16x16x32_bf16(vf, pf, o[db], 0, 0, 0);
                }
            }
        }
    }
    float i4[4];
#pragma unroll
    for (int rg = 0; rg < 4; ++rg) i4[rg] = 1.f / lrun[rg];
    float s0 = __shfl(i4[0], (lc >> 2) << 4, 64);
    float s1 = __shfl(i4[1], (lc >> 2) << 4, 64);
    float s2 = __shfl(i4[2], (lc >> 2) << 4, 64);
    float s3 = __shfl(i4[3], (lc >> 2) << 4, 64);
    float myi = (lc & 2) ? ((lc & 1) ? s3 : s2) : ((lc & 1) ? s1 : s0);
#pragma unroll
    for (int db = 0; db < 4; ++db)
#pragma unroll
        for (int rg = 0; rg < 4; ++rg)
            Ps[wv][lc][db * 16 + lr * 4 + rg] = f2bf(o[db][rg] * myi);
    const int il2 = lane >> 2, dsg = (lane & 3) << 4;
    bf8_t e0 = *(const bf8_t*)&Ps[wv][il2][dsg];
    bf8_t e1 = *(const bf8_t*)&Ps[wv][il2][dsg + 8];
    ushort* dst = ao + ((size_t)(iw + il2) * 32 + b) * 512 + h * 64 + dsg;
    *(bf8_t*)dst = e0;
    *(bf8_t*)(dst + 8) = e1;
}

// ---------------------------------------------------------------------------
extern "C" void kernel_launch(void* const* d_in, const int* in_sizes, int n_in,
                              void* d_out, int out_size, void* d_ws, size_t ws_size,
                              hipStream_t stream)
{
    const float* x       = (const float*)d_in[0];
    const int*   action  = (const int*)d_in[1];
    const float* mems    = (const float*)d_in[4];
    const float* act_emb = (const float*)d_in[5];
    const float* stem_w1 = (const float*)d_in[6];
    const float* sln1g   = (const float*)d_in[7];
    const float* sln1b   = (const float*)d_in[8];
    const float* stem_w2 = (const float*)d_in[9];
    const float* sln2g   = (const float*)d_in[10];
    const float* sln2b   = (const float*)d_in[11];
    const float* lnfg    = (const float*)d_in[12];
    const float* lnfb    = (const float*)d_in[13];
    const float* ub      = (const float*)d_in[14];
    const float* vb      = (const float*)d_in[15];
    const float* Wqkv    = (const float*)d_in[16];
    const float* Wr      = (const float*)d_in[17];
    const float* Wo      = (const float*)d_in[18];
    const float* ln1g    = (const float*)d_in[19];
    const float* ln1b    = (const float*)d_in[20];
    const float* W1      = (const float*)d_in[21];
    const float* b1      = (const float*)d_in[22];
    const float* W2      = (const float*)d_in[23];
    const float* b2      = (const float*)d_in[24];
    const float* ln2g    = (const float*)d_in[25];
    const float* ln2b    = (const float*)d_in[26];
    float* out = (float*)d_out;

    // ---- workspace layout (bytes), total ~116.1 MB ----
    char* W = (char*)d_ws;
    float*  cur32 = (float*) (W + 0);           // 16 MB residual f32
    float*  g32   = (float*) (W + 16777216);    // 16 MB gemm f32 scratch (hosts memsb)
    ushort* curb  = (ushort*)(W + 33554432);    //  8 MB cur bf16
    ushort* h1b   = (ushort*)(W + 41943040);    //  8 MB h1/ao bf16
    ushort* qkvb  = (ushort*)(W + 50331648);    // 24 MB qkv [8192][1536]
    ushort* kvm   = (ushort*)(W + 75497472);    // 16 MB kv mems [8192][1024]
    ushort* rbuf  = (ushort*)(W + 92274688);    // 512 KB
    ushort* peb   = (ushort*)(W + 92798976);    // 512 KB
    ushort* wts   = (ushort*)(W + 93323264);    // 27 MB transposed bf16 weights
    ushort* xcatb = qkvb;                       // stem alias
    ushort* ff1b  = qkvb;                       // FF1 alias (qkv+kvm dead post-attn)
    ushort* memsb = (ushort*)g32;               // alias (g32 dead at layer start)
    ushort* w1t    = wts;                       // [512][576]
    ushort* w2t    = wts + 294912;              // [512][512]
    ushort* wqkvT  = wts + 557056;              // [4][1536][512]
    ushort* wrT    = wts + 3702784;             // [4][512][512]
    ushort* woT    = wts + 4751360;             // [4][512][512]
    ushort* w1T    = wts + 5799936;             // [4][2048][512]
    ushort* w2T    = wts + 9994240;             // [4][512][2048]

    dim3 blk(256);
    wtrans<<<dim3(16, 18, 1), blk, 0, stream>>>(stem_w1, w1t, 576, 512);
    wtrans<<<dim3(16, 16, 1), blk, 0, stream>>>(stem_w2, w2t, 512, 512);
    wtrans<<<dim3(48, 16, 4), blk, 0, stream>>>(Wqkv, wqkvT, 512, 1536);
    wtrans<<<dim3(16, 16, 4), blk, 0, stream>>>(Wr, wrT, 512, 512);
    wtrans<<<dim3(16, 16, 4), blk, 0, stream>>>(Wo, woT, 512, 512);
    wtrans<<<dim3(64, 16, 4), blk, 0, stream>>>(W1, w1T, 512, 2048);
    wtrans<<<dim3(16, 64, 4), blk, 0, stream>>>(W2, w2T, 2048, 512);
    build_posemb<<<1024, blk, 0, stream>>>(peb);

    build_xcat<<<18432, blk, 0, stream>>>(x, action, act_emb, xcatb);
    gemm_bf<false, false, false><<<dim3(4, 64), blk, 0, stream>>>(xcatb, 576, w1t, 576, nullptr, g32, 512, 8192, 512, 576);
    ln_k<0, false><<<2048, blk, 0, stream>>>(g32, nullptr, sln1g, sln1b, nullptr, curb, 1e-5f, 1);
    gemm_bf<false, false, false><<<dim3(4, 64), blk, 0, stream>>>(curb, 512, w2t, 512, nullptr, g32, 512, 8192, 512, 512);
    ln_stem2<<<2048, blk, 0, stream>>>(g32, sln2g, sln2b, lnfg, lnfb, cur32, curb);

    for (int l = 0; l < 4; ++l) {
        const ushort* wqkvT_l = wqkvT + (size_t)l * 786432;
        convk<<<4096, blk, 0, stream>>>(mems + (size_t)l * 4194304, memsb);
        gemm_bf<false, false, true><<<dim3(12, 64), blk, 0, stream>>>(curb, 512, wqkvT_l, 512, nullptr, qkvb, 1536, 8192, 1536, 512);
        gemm_bf<false, false, true><<<dim3(8, 64), blk, 0, stream>>>(memsb, 512, wqkvT_l + 262144, 512, nullptr, kvm, 1024, 8192, 1024, 512);
        gemm_bf<false, false, true><<<dim3(4, 4), blk, 0, stream>>>(peb, 512, wrT + (size_t)l * 262144, 512, nullptr, rbuf, 512, 512, 512, 512);
        attn_mfma<<<512, dim3(512), 0, stream>>>(qkvb, kvm, rbuf, ub, vb, h1b);
        gemm_bf<false, false, false><<<dim3(4, 64), blk, 0, stream>>>(h1b, 512, woT + (size_t)l * 262144, 512, nullptr, g32, 512, 8192, 512, 512);
        ln_k<1, false><<<2048, blk, 0, stream>>>(g32, cur32, ln1g + l * 512, ln1b + l * 512, nullptr, h1b, 1e-5f, 0);
        gemm_bf<true, true, true><<<dim3(16, 64), blk, 0, stream>>>(h1b, 512, w1T + (size_t)l * 1048576, 512, b1 + l * 2048, ff1b, 2048, 8192, 2048, 512);
        gemm_bf<true, false, false><<<dim3(4, 64), blk, 0, stream>>>(ff1b, 2048, w2T + (size_t)l * 1048576, 2048, b2 + l * 512, g32, 512, 8192, 512, 2048);
        if (l == 3)
            ln_k<2, true><<<2048, blk, 0, stream>>>(g32, h1b, ln2g + l * 512, ln2b + l * 512, out, nullptr, 1e-5f, 0);
        else
            ln_k<2, false><<<2048, blk, 0, stream>>>(g32, h1b, ln2g + l * 512, ln2b + l * 512, cur32, curb, 1e-5f, 0);
    }
}